// Round 2
// baseline (1106.580 us; speedup 1.0000x reference)
//
#include <hip/hip_runtime.h>
#include <hip/hip_fp16.h>
#include <math.h>

#define B 2
#define T 2048
#define C 384
#define H 6
#define HD 64
#define BHT (B*H*T)                    // 24576
#define LOGT 7.6246189861593985f       // log(2048)

typedef __half half_t;

// ---------------- block reduction helpers (256 threads = 4 waves) -------------
__device__ __forceinline__ float block_reduce_sum(float v) {
    __shared__ float sm[4];
    int lane = threadIdx.x & 63, wid = threadIdx.x >> 6;
#pragma unroll
    for (int o = 32; o > 0; o >>= 1) v += __shfl_down(v, o, 64);
    __syncthreads();
    if (lane == 0) sm[wid] = v;
    __syncthreads();
    return sm[0] + sm[1] + sm[2] + sm[3];
}

__device__ __forceinline__ float block_reduce_max(float v) {
    __shared__ float sm[4];
    int lane = threadIdx.x & 63, wid = threadIdx.x >> 6;
#pragma unroll
    for (int o = 32; o > 0; o >>= 1) v = fmaxf(v, __shfl_down(v, o, 64));
    __syncthreads();
    if (lane == 0) sm[wid] = v;
    __syncthreads();
    return fmaxf(fmaxf(sm[0], sm[1]), fmaxf(sm[2], sm[3]));
}

// ---------------- zero-fill helpers ------------------------------------------
__global__ __launch_bounds__(256) void zero4_kernel(uint4* __restrict__ p) {
    p[(size_t)blockIdx.x * 256 + threadIdx.x] = make_uint4(0u, 0u, 0u, 0u);
}
__global__ __launch_bounds__(256) void zerof_kernel(float* __restrict__ p) {
    p[(size_t)blockIdx.x * 256 + threadIdx.x] = 0.f;
}

// ---------------- add_time + layernorm over C+1=385 features ------------------
__global__ __launch_bounds__(256) void addtime_ln_kernel(
        const float* __restrict__ src, const float* __restrict__ tptr,
        const float* __restrict__ w, const float* __restrict__ bb,
        float* __restrict__ dst) {
    const int n = C + 1;               // 385
    int row = blockIdx.x;              // over B*T
    const float* srow = src + (size_t)row * C;
    float tval = tptr[0];
    int i0 = threadIdx.x;              // 0..255  (< C always)
    int i1 = threadIdx.x + 256;        // 256..511
    float v0 = srow[i0];
    bool has1 = (i1 < n);
    float v1 = 0.f;
    if (has1) v1 = (i1 < C) ? srow[i1] : tval;
    float s  = block_reduce_sum(v0 + v1);
    float sq = block_reduce_sum(v0*v0 + v1*v1);
    float mean = s / n;
    float var  = sq / n - mean * mean;
    float rstd = rsqrtf(var + 1e-5f);
    float* drow = dst + (size_t)row * n;
    drow[i0] = (v0 - mean) * rstd * w[i0] + bb[i0];
    if (has1) drow[i1] = (v1 - mean) * rstd * w[i1] + bb[i1];
}

// ---------------- generic fp32 tiled GEMM: out = A(MxK) @ W(KxN) + bias -------
// ACT: 0 = none, 1 = exact gelu
template<int ACT>
__global__ __launch_bounds__(256) void gemm_kernel(
        const float* __restrict__ A, const float* __restrict__ W,
        const float* __restrict__ bias, float* __restrict__ out,
        int M, int N, int K) {
    __shared__ __align__(16) float As[16][68];
    __shared__ __align__(16) float Ws[16][68];
    int tid = threadIdx.x;
    int tx = tid & 15, ty = tid >> 4;
    int m0 = blockIdx.y * 64, n0 = blockIdx.x * 64;
    float acc[4][4] = {};
    for (int k0 = 0; k0 < K; k0 += 16) {
        __syncthreads();
#pragma unroll
        for (int l = 0; l < 4; ++l) {
            int e = tid * 4 + l;
            int kk = e & 15, mm = e >> 4;
            As[kk][mm] = (k0 + kk < K) ? A[(size_t)(m0 + mm) * K + k0 + kk] : 0.f;
            int nn = e & 63, kw = e >> 6;
            Ws[kw][nn] = (k0 + kw < K) ? W[(size_t)(k0 + kw) * N + n0 + nn] : 0.f;
        }
        __syncthreads();
#pragma unroll
        for (int kk = 0; kk < 16; ++kk) {
            float4 a4 = *reinterpret_cast<const float4*>(&As[kk][ty * 4]);
            float4 b4 = *reinterpret_cast<const float4*>(&Ws[kk][tx * 4]);
            float a[4]  = {a4.x, a4.y, a4.z, a4.w};
            float bv[4] = {b4.x, b4.y, b4.z, b4.w};
#pragma unroll
            for (int i2 = 0; i2 < 4; ++i2)
#pragma unroll
                for (int j2 = 0; j2 < 4; ++j2)
                    acc[i2][j2] += a[i2] * bv[j2];
        }
    }
#pragma unroll
    for (int i2 = 0; i2 < 4; ++i2) {
        int mrow = m0 + ty * 4 + i2;
#pragma unroll
        for (int j2 = 0; j2 < 4; ++j2) {
            int ncol = n0 + tx * 4 + j2;
            float val = acc[i2][j2] + bias[ncol];
            if (ACT == 1) val = 0.5f * val * (1.f + erff(val * 0.70710678118654752f));
            out[(size_t)mrow * N + ncol] = val;
        }
    }
}

// ---------------- QK^T pass 1: per-row max + sumexp (causal) ------------------
__global__ __launch_bounds__(256) void qk_pass1(const float* __restrict__ qkv,
        float* __restrict__ mrow, float* __restrict__ zrow) {
    int qt = blockIdx.x, h = blockIdx.y, b = blockIdx.z;
    int bh = b * H + h;
    int tid = threadIdx.x, tx = tid & 15, ty = tid >> 4;
    __shared__ __align__(16) float Qs[64][68];
    __shared__ __align__(16) float Ks[64][68];
    __shared__ float red_m[64][17];
    __shared__ float red_z[64][17];
    const float* qbase = qkv + ((size_t)b * T + qt * 64) * (3 * C) + h * HD;
#pragma unroll
    for (int l = 0; l < 16; ++l) {
        int idx = l * 256 + tid;
        int d = idx & 63, i = idx >> 6;
        Qs[d][i] = qbase[(size_t)i * (3 * C) + d];
    }
    float m_t[4], z_t[4];
#pragma unroll
    for (int r = 0; r < 4; ++r) { m_t[r] = -1e30f; z_t[r] = 0.f; }
    for (int jt = 0; jt <= qt; ++jt) {
        const float* kbase = qkv + ((size_t)b * T + jt * 64) * (3 * C) + C + h * HD;
        __syncthreads();
#pragma unroll
        for (int l = 0; l < 16; ++l) {
            int idx = l * 256 + tid;
            int d = idx & 63, j = idx >> 6;
            Ks[d][j] = kbase[(size_t)j * (3 * C) + d];
        }
        __syncthreads();
        float acc[4][4] = {};
#pragma unroll 8
        for (int d = 0; d < 64; ++d) {
            float4 a4 = *reinterpret_cast<const float4*>(&Qs[d][ty * 4]);
            float4 b4 = *reinterpret_cast<const float4*>(&Ks[d][tx * 4]);
            float a[4]  = {a4.x, a4.y, a4.z, a4.w};
            float bv[4] = {b4.x, b4.y, b4.z, b4.w};
#pragma unroll
            for (int i2 = 0; i2 < 4; ++i2)
#pragma unroll
                for (int j2 = 0; j2 < 4; ++j2)
                    acc[i2][j2] += a[i2] * bv[j2];
        }
        bool diag = (jt == qt);
#pragma unroll
        for (int i2 = 0; i2 < 4; ++i2) {
            int gi = ty * 4 + i2;
            float s[4]; float tm = -1e30f;
#pragma unroll
            for (int j2 = 0; j2 < 4; ++j2) {
                int gj = tx * 4 + j2;
                float vsc = acc[i2][j2] * 0.125f;
                if (diag && gj > gi) vsc = -1e30f;
                s[j2] = vsc;
                tm = fmaxf(tm, vsc);
            }
            float nm = fmaxf(m_t[i2], tm);
            float zadd = 0.f;
#pragma unroll
            for (int j2 = 0; j2 < 4; ++j2)
                zadd += (s[j2] > -1e29f) ? __expf(s[j2] - nm) : 0.f;
            z_t[i2] = z_t[i2] * __expf(m_t[i2] - nm) + zadd;
            m_t[i2] = nm;
        }
    }
#pragma unroll
    for (int i2 = 0; i2 < 4; ++i2) {
        red_m[ty * 4 + i2][tx] = m_t[i2];
        red_z[ty * 4 + i2][tx] = z_t[i2];
    }
    __syncthreads();
    if (tid < 64) {
        float mm = red_m[tid][0];
#pragma unroll
        for (int k = 1; k < 16; ++k) mm = fmaxf(mm, red_m[tid][k]);
        float zz = 0.f;
#pragma unroll
        for (int k = 0; k < 16; ++k) zz += red_z[tid][k] * __expf(red_m[tid][k] - mm);
        mrow[(size_t)bh * T + qt * 64 + tid] = mm;
        zrow[(size_t)bh * T + qt * 64 + tid] = zz;
    }
}

// ---------------- QK^T pass 2: write normalized softmax rows to fp16 c --------
__global__ __launch_bounds__(256) void qk_pass2(const float* __restrict__ qkv,
        const float* __restrict__ mrow, const float* __restrict__ zrow,
        half_t* __restrict__ c_h) {
    int qt = blockIdx.x, h = blockIdx.y, b = blockIdx.z;
    int bh = b * H + h;
    int tid = threadIdx.x, tx = tid & 15, ty = tid >> 4;
    __shared__ __align__(16) float Qs[64][68];
    __shared__ __align__(16) float Ks[64][68];
    const float* qbase = qkv + ((size_t)b * T + qt * 64) * (3 * C) + h * HD;
#pragma unroll
    for (int l = 0; l < 16; ++l) {
        int idx = l * 256 + tid;
        int d = idx & 63, i = idx >> 6;
        Qs[d][i] = qbase[(size_t)i * (3 * C) + d];
    }
    float mI[4], zI[4];
#pragma unroll
    for (int i2 = 0; i2 < 4; ++i2) {
        size_t gr = (size_t)bh * T + qt * 64 + ty * 4 + i2;
        mI[i2] = mrow[gr];
        zI[i2] = 1.f / zrow[gr];
    }
    for (int jt = 0; jt <= qt; ++jt) {
        const float* kbase = qkv + ((size_t)b * T + jt * 64) * (3 * C) + C + h * HD;
        __syncthreads();
#pragma unroll
        for (int l = 0; l < 16; ++l) {
            int idx = l * 256 + tid;
            int d = idx & 63, j = idx >> 6;
            Ks[d][j] = kbase[(size_t)j * (3 * C) + d];
        }
        __syncthreads();
        float acc[4][4] = {};
#pragma unroll 8
        for (int d = 0; d < 64; ++d) {
            float4 a4 = *reinterpret_cast<const float4*>(&Qs[d][ty * 4]);
            float4 b4 = *reinterpret_cast<const float4*>(&Ks[d][tx * 4]);
            float a[4]  = {a4.x, a4.y, a4.z, a4.w};
            float bv[4] = {b4.x, b4.y, b4.z, b4.w};
#pragma unroll
            for (int i2 = 0; i2 < 4; ++i2)
#pragma unroll
                for (int j2 = 0; j2 < 4; ++j2)
                    acc[i2][j2] += a[i2] * bv[j2];
        }
        bool diag = (jt == qt);
#pragma unroll
        for (int i2 = 0; i2 < 4; ++i2) {
            int gi = ty * 4 + i2;
            float cv[4];
#pragma unroll
            for (int j2 = 0; j2 < 4; ++j2) {
                int gj = tx * 4 + j2;
                float vsc = acc[i2][j2] * 0.125f;
                cv[j2] = (diag && gj > gi) ? 0.f : __expf(vsc - mI[i2]) * zI[i2];
            }
            union { __half2 h2[2]; uint2 u; } pk;
            pk.h2[0] = __floats2half2_rn(cv[0], cv[1]);
            pk.h2[1] = __floats2half2_rn(cv[2], cv[3]);
            size_t off = ((size_t)bh * T + qt * 64 + gi) * T + jt * 64 + tx * 4;
            *reinterpret_cast<uint2*>(c_h + off) = pk.u;
        }
    }
}

// ---------------- sinkhorn row pass: u_i = -logT - LSE_j(c_ij + v_j) ----------
__global__ __launch_bounds__(256) void row_u_kernel(const half_t* __restrict__ c,
        const float* __restrict__ v, float* __restrict__ u) {
    int row = blockIdx.x;              // (b*H+h)*T + i
    int bh = row >> 11;                // / T
    int tid = threadIdx.x;
    const half_t* crow = c + (size_t)row * T;
    const float* vrow = v + (size_t)bh * T;
    float4 raw = reinterpret_cast<const float4*>(crow)[tid];   // 8 halves
    const __half2* h2p = reinterpret_cast<const __half2*>(&raw);
    float xs[8];
    float mx = -1e30f;
#pragma unroll
    for (int p = 0; p < 4; ++p) {
        float2 cf = __half22float2(h2p[p]);
        int j = tid * 8 + p * 2;
        xs[p*2]   = cf.x + vrow[j];
        xs[p*2+1] = cf.y + vrow[j + 1];
        mx = fmaxf(mx, fmaxf(xs[p*2], xs[p*2+1]));
    }
    float Mx = block_reduce_max(mx);
    float sum = 0.f;
#pragma unroll
    for (int k = 0; k < 8; ++k) sum += __expf(xs[k] - Mx);
    float S = block_reduce_sum(sum);
    if (tid == 0) u[row] = -LOGT - (Mx + logf(S));
}

// ---------------- sinkhorn col pass: partial sums of exp(c_ij + u_i) ----------
__global__ __launch_bounds__(256) void col_accum_kernel(const half_t* __restrict__ c,
        const float* __restrict__ u, float* __restrict__ acc) {
    int j  = blockIdx.x * 256 + threadIdx.x;
    int r0 = blockIdx.y * 128;
    int bh = blockIdx.z;
    const half_t* cb = c + (size_t)bh * T * T;
    const float* ub = u + (size_t)bh * T;
    float a = 0.f;
#pragma unroll 4
    for (int r = 0; r < 128; ++r)
        a += __expf(__half2float(cb[(size_t)(r0 + r) * T + j]) + ub[r0 + r]);
    atomicAdd(&acc[(size_t)bh * T + j], a);
}

__global__ __launch_bounds__(256) void v_finalize_kernel(const float* __restrict__ acc,
        float* __restrict__ v) {
    int idx = blockIdx.x * 256 + threadIdx.x;
    v[idx] = -LOGT - logf(acc[idx]);
}

// ---------------- y = (exp(c+u+v)*T) @ V, tiled 64x64 -------------------------
__global__ __launch_bounds__(256) void pv_tiled(const half_t* __restrict__ c_h,
        const float* __restrict__ u, const float* __restrict__ v,
        const float* __restrict__ qkv, float* __restrict__ y) {
    int qt = blockIdx.x, h = blockIdx.y, b = blockIdx.z;
    int bh = b * H + h;
    int tid = threadIdx.x, tx = tid & 15, ty = tid >> 4;
    __shared__ __align__(16) float Ps[64][68];   // Ps[j][i]
    __shared__ __align__(16) float Vs[64][68];   // Vs[j][d]
    __shared__ float us[64];
    __shared__ float vs[64];
    if (tid < 64) us[tid] = u[(size_t)bh * T + qt * 64 + tid];
    float acc[4][4] = {};
    const half_t* crow0 = c_h + ((size_t)bh * T + qt * 64) * T;
    for (int jt = 0; jt < T / 64; ++jt) {
        __syncthreads();
        if (tid < 64) vs[tid] = v[(size_t)bh * T + jt * 64 + tid];
        __syncthreads();
#pragma unroll
        for (int l = 0; l < 16; ++l) {
            int idx = l * 256 + tid;
            int j = idx & 63, i = idx >> 6;
            float cc = __half2float(crow0[(size_t)i * T + jt * 64 + j]);
            Ps[j][i] = __expf(cc + us[i] + vs[j]);
        }
        const float* vbase = qkv + ((size_t)b * T + jt * 64) * (3 * C) + 2 * C + h * HD;
#pragma unroll
        for (int l = 0; l < 16; ++l) {
            int idx = l * 256 + tid;
            int d = idx & 63, j = idx >> 6;
            Vs[j][d] = vbase[(size_t)j * (3 * C) + d];
        }
        __syncthreads();
#pragma unroll 8
        for (int j = 0; j < 64; ++j) {
            float4 a4 = *reinterpret_cast<const float4*>(&Ps[j][ty * 4]);
            float4 b4 = *reinterpret_cast<const float4*>(&Vs[j][tx * 4]);
            float a[4]  = {a4.x, a4.y, a4.z, a4.w};
            float bv[4] = {b4.x, b4.y, b4.z, b4.w};
#pragma unroll
            for (int i2 = 0; i2 < 4; ++i2)
#pragma unroll
                for (int j2 = 0; j2 < 4; ++j2)
                    acc[i2][j2] += a[i2] * bv[j2];
        }
    }
#pragma unroll
    for (int i2 = 0; i2 < 4; ++i2)
#pragma unroll
        for (int j2 = 0; j2 < 4; ++j2)
            y[((size_t)b * T + qt * 64 + ty * 4 + i2) * C + h * HD + tx * 4 + j2]
                = acc[i2][j2] * 2048.f;
}

// -----------------------------------------------------------------------------
extern "C" void kernel_launch(void* const* d_in, const int* in_sizes, int n_in,
                              void* d_out, int out_size, void* d_ws, size_t ws_size,
                              hipStream_t stream) {
    (void)in_sizes; (void)n_in; (void)out_size;
    const float* x      = (const float*)d_in[0];
    const float* t      = (const float*)d_in[1];
    const float* ln1_w  = (const float*)d_in[2];
    const float* ln1_b  = (const float*)d_in[3];
    const float* attn_w = (const float*)d_in[4];
    const float* attn_b = (const float*)d_in[5];
    const float* proj_w = (const float*)d_in[6];
    const float* proj_b = (const float*)d_in[7];
    const float* ln2_w  = (const float*)d_in[8];
    const float* ln2_b  = (const float*)d_in[9];
    const float* fc_w   = (const float*)d_in[10];
    const float* fc_b   = (const float*)d_in[11];
    const float* fc2_w  = (const float*)d_in[12];
    const float* fc2_b  = (const float*)d_in[13];
    float* out = (float*)d_out;

    // ---- workspace layout (126,337,024 bytes total) ----
    const size_t C_BYTES = (size_t)B*H*T*T*sizeof(half_t);     // 100,663,296
    if (ws_size < 126337024ull) return;   // diagnostic guard: ws too small
    char* wsb = (char*)d_ws;
    half_t* c_h  = (half_t*)wsb;
    float* qkvb  = (float*)(wsb + C_BYTES);                    // 4,718,592 fl
    float* buf1  = qkvb + (size_t)B*T*3*C;                     // 1,576,960 fl (xn / yb)
    float* u     = buf1 + (size_t)B*T*(C+1);
    float* vv    = u    + BHT;
    float* cacc  = vv   + BHT;
    float* mrow  = cacc + BHT;
    float* zrow  = mrow + BHT;
    // aliases (dead-buffer reuse):
    float* xn = buf1;                 // live: ln1 -> qkv gemm
    float* yb = buf1;                 // live: pv -> proj (xn dead)
    float* hb = qkvb;                 // live: proj -> ln2 (qkvb dead after pv)
    float* hn = qkvb + (size_t)B*T*C; // live: ln2 -> fc
    float* mb = (float*)wsb;          // live: fc -> fc2 (c dead after pv)

    const int M = B * T;  // 4096

    // zero c (fp16 zeros) -- upper-triangular tiles stay zero
    zero4_kernel<<<24576, 256, 0, stream>>>((uint4*)c_h);

    // attention sub-block
    addtime_ln_kernel<<<M, 256, 0, stream>>>(x, t, ln1_w, ln1_b, xn);
    gemm_kernel<0><<<dim3(3*C/64, M/64), 256, 0, stream>>>(
        xn, attn_w, attn_b, qkvb, M, 3*C, C+1);
    qk_pass1<<<dim3(T/64, H, B), 256, 0, stream>>>(qkvb, mrow, zrow);
    qk_pass2<<<dim3(T/64, H, B), 256, 0, stream>>>(qkvb, mrow, zrow, c_h);

    // sinkhorn: u at iters 0,2,4; v at iters 1,3,5
    zerof_kernel<<<BHT/256, 256, 0, stream>>>(vv);
    row_u_kernel<<<BHT, 256, 0, stream>>>(c_h, vv, u);                     // iter 0
    for (int it = 0; it < 3; ++it) {
        zerof_kernel<<<BHT/256, 256, 0, stream>>>(cacc);
        col_accum_kernel<<<dim3(T/256, T/128, B*H), 256, 0, stream>>>(c_h, u, cacc);
        v_finalize_kernel<<<BHT/256, 256, 0, stream>>>(cacc, vv);          // iters 1,3,5
        if (it < 2)
            row_u_kernel<<<BHT, 256, 0, stream>>>(c_h, vv, u);             // iters 2,4
    }

    pv_tiled<<<dim3(T/64, H, B), 256, 0, stream>>>(c_h, u, vv, qkvb, yb);
    gemm_kernel<0><<<dim3(C/64, M/64), 256, 0, stream>>>(
        yb, proj_w, proj_b, hb, M, C, C);

    // MLP sub-block
    addtime_ln_kernel<<<M, 256, 0, stream>>>(hb, t, ln2_w, ln2_b, hn);
    gemm_kernel<1><<<dim3(4*C/64, M/64), 256, 0, stream>>>(
        hn, fc_w, fc_b, mb, M, 4*C, C+1);
    gemm_kernel<0><<<dim3(C/64, M/64), 256, 0, stream>>>(
        mb, fc2_w, fc2_b, out, M, C, 4*C);
}

// Round 3
// 757.666 us; speedup vs baseline: 1.4605x; 1.4605x over previous
//
#include <hip/hip_runtime.h>
#include <hip/hip_fp16.h>
#include <math.h>

#define B 2
#define T 2048
#define C 384
#define H 6
#define HD 64
#define BHT (B*H*T)                    // 24576
#define LOGT 7.6246189861593985f       // log(2048)

typedef __half half_t;
typedef _Float16 f16x8 __attribute__((ext_vector_type(8)));
typedef float f32x4 __attribute__((ext_vector_type(4)));

// ---------------- block reduction helpers (256 threads = 4 waves) -------------
__device__ __forceinline__ float block_reduce_sum(float v) {
    __shared__ float sm[4];
    int lane = threadIdx.x & 63, wid = threadIdx.x >> 6;
#pragma unroll
    for (int o = 32; o > 0; o >>= 1) v += __shfl_down(v, o, 64);
    __syncthreads();
    if (lane == 0) sm[wid] = v;
    __syncthreads();
    return sm[0] + sm[1] + sm[2] + sm[3];
}

__device__ __forceinline__ float block_reduce_max(float v) {
    __shared__ float sm[4];
    int lane = threadIdx.x & 63, wid = threadIdx.x >> 6;
#pragma unroll
    for (int o = 32; o > 0; o >>= 1) v = fmaxf(v, __shfl_down(v, o, 64));
    __syncthreads();
    if (lane == 0) sm[wid] = v;
    __syncthreads();
    return fmaxf(fmaxf(sm[0], sm[1]), fmaxf(sm[2], sm[3]));
}

// ---------------- zero-fill helper -------------------------------------------
__global__ __launch_bounds__(256) void zero4_kernel(uint4* __restrict__ p) {
    p[(size_t)blockIdx.x * 256 + threadIdx.x] = make_uint4(0u, 0u, 0u, 0u);
}
__global__ __launch_bounds__(256) void zerof_kernel(float* __restrict__ p) {
    p[(size_t)blockIdx.x * 256 + threadIdx.x] = 0.f;
}

// ------- weight convert+transpose: W (K×N fp32) -> Wt (N×KP f16, zero-pad) ----
__global__ __launch_bounds__(256) void convtrans_kernel(const float* __restrict__ W,
        _Float16* __restrict__ Wt, int K, int N, int KP) {
    __shared__ float tile[32][33];
    int k0 = blockIdx.x * 32, n0 = blockIdx.y * 32;
    int tx = threadIdx.x & 31, ty = threadIdx.x >> 5;   // 32×8
#pragma unroll
    for (int i = 0; i < 4; ++i) {
        int k = k0 + ty + i * 8, n = n0 + tx;
        tile[ty + i * 8][tx] = (k < K && n < N) ? W[(size_t)k * N + n] : 0.f;
    }
    __syncthreads();
#pragma unroll
    for (int i = 0; i < 4; ++i) {
        int n = n0 + ty + i * 8, k = k0 + tx;
        if (n < N && k < KP) Wt[(size_t)n * KP + k] = (_Float16)tile[tx][ty + i * 8];
    }
}

// ---------------- add_time + layernorm -> f16 rows (stride KP, zero-padded) ---
__global__ __launch_bounds__(256) void addtime_ln_f16(
        const float* __restrict__ src, const float* __restrict__ tptr,
        const float* __restrict__ w, const float* __restrict__ bb,
        _Float16* __restrict__ dst, int KP) {
    const int n = C + 1;               // 385
    int row = blockIdx.x;              // over B*T
    const float* srow = src + (size_t)row * C;
    float tval = tptr[0];
    int i0 = threadIdx.x;              // 0..255
    int i1 = threadIdx.x + 256;        // 256..511
    float v0 = srow[i0];
    bool has1 = (i1 < n);
    float v1 = 0.f;
    if (has1) v1 = (i1 < C) ? srow[i1] : tval;
    float s  = block_reduce_sum(v0 + v1);
    float sq = block_reduce_sum(v0*v0 + v1*v1);
    float mean = s / n;
    float var  = sq / n - mean * mean;
    float rstd = rsqrtf(var + 1e-5f);
    _Float16* drow = dst + (size_t)row * KP;
    drow[i0] = (_Float16)((v0 - mean) * rstd * w[i0] + bb[i0]);
    if (has1) drow[i1] = (_Float16)((v1 - mean) * rstd * w[i1] + bb[i1]);
    else if (i1 < KP) drow[i1] = (_Float16)0.f;   // zero pad 385..KP-1
}

// ---------------- f16 MFMA GEMM: out = A(M×KP) @ Wt(N×KP)^T + bias ------------
// ACT: 0 none, 1 exact gelu.  OUT_T: float or _Float16.
template<int ACT, typename OUT_T>
__global__ __launch_bounds__(256) void mfma_gemm(
        const _Float16* __restrict__ A, const _Float16* __restrict__ Wt,
        const float* __restrict__ bias, OUT_T* __restrict__ out,
        int M, int N, int KP) {
    __shared__ __align__(16) _Float16 As[64][40];   // +8 pad: 2-way-free banks
    __shared__ __align__(16) _Float16 Bs[64][40];
    int tid = threadIdx.x;
    int lane = tid & 63, wave = tid >> 6;
    int wr = wave >> 1, wc = wave & 1;              // 2×2 waves, 32×32 each
    int m0 = blockIdx.y * 64, n0 = blockIdx.x * 64;
    int arow = tid >> 2, seg = tid & 3;
    int lrow = lane & 15, lseg = lane >> 4;
    f32x4 acc[2][2] = {};
    for (int k0 = 0; k0 < KP; k0 += 32) {
        __syncthreads();
        *(f16x8*)&As[arow][seg * 8] =
            *(const f16x8*)&A[(size_t)(m0 + arow) * KP + k0 + seg * 8];
        *(f16x8*)&Bs[arow][seg * 8] =
            *(const f16x8*)&Wt[(size_t)(n0 + arow) * KP + k0 + seg * 8];
        __syncthreads();
        f16x8 af[2], bf[2];
#pragma unroll
        for (int i = 0; i < 2; ++i)
            af[i] = *(const f16x8*)&As[wr * 32 + i * 16 + lrow][lseg * 8];
#pragma unroll
        for (int j = 0; j < 2; ++j)
            bf[j] = *(const f16x8*)&Bs[wc * 32 + j * 16 + lrow][lseg * 8];
#pragma unroll
        for (int i = 0; i < 2; ++i)
#pragma unroll
            for (int j = 0; j < 2; ++j)
                acc[i][j] = __builtin_amdgcn_mfma_f32_16x16x32_f16(
                    af[i], bf[j], acc[i][j], 0, 0, 0);
    }
    int lcol = lane & 15, lr4 = (lane >> 4) * 4;
#pragma unroll
    for (int i = 0; i < 2; ++i)
#pragma unroll
        for (int j = 0; j < 2; ++j) {
            int col = n0 + wc * 32 + j * 16 + lcol;
            float bv = bias[col];
#pragma unroll
            for (int r = 0; r < 4; ++r) {
                int row = m0 + wr * 32 + i * 16 + lr4 + r;
                float v = acc[i][j][r] + bv;
                if (ACT == 1) v = 0.5f * v * (1.f + erff(v * 0.70710678118654752f));
                out[(size_t)row * N + col] = (OUT_T)v;
            }
        }
}

// ---------------- QK^T pass 1: per-row max + sumexp (causal) ------------------
__global__ __launch_bounds__(256) void qk_pass1(const float* __restrict__ qkv,
        float* __restrict__ mrow, float* __restrict__ zrow) {
    int qt = blockIdx.x, h = blockIdx.y, b = blockIdx.z;
    int bh = b * H + h;
    int tid = threadIdx.x, tx = tid & 15, ty = tid >> 4;
    __shared__ __align__(16) float Qs[64][68];
    __shared__ __align__(16) float Ks[64][68];
    __shared__ float red_m[64][17];
    __shared__ float red_z[64][17];
    const float* qbase = qkv + ((size_t)b * T + qt * 64) * (3 * C) + h * HD;
#pragma unroll
    for (int l = 0; l < 16; ++l) {
        int idx = l * 256 + tid;
        int d = idx & 63, i = idx >> 6;
        Qs[d][i] = qbase[(size_t)i * (3 * C) + d];
    }
    float m_t[4], z_t[4];
#pragma unroll
    for (int r = 0; r < 4; ++r) { m_t[r] = -1e30f; z_t[r] = 0.f; }
    for (int jt = 0; jt <= qt; ++jt) {
        const float* kbase = qkv + ((size_t)b * T + jt * 64) * (3 * C) + C + h * HD;
        __syncthreads();
#pragma unroll
        for (int l = 0; l < 16; ++l) {
            int idx = l * 256 + tid;
            int d = idx & 63, j = idx >> 6;
            Ks[d][j] = kbase[(size_t)j * (3 * C) + d];
        }
        __syncthreads();
        float acc[4][4] = {};
#pragma unroll 8
        for (int d = 0; d < 64; ++d) {
            float4 a4 = *reinterpret_cast<const float4*>(&Qs[d][ty * 4]);
            float4 b4 = *reinterpret_cast<const float4*>(&Ks[d][tx * 4]);
            float a[4]  = {a4.x, a4.y, a4.z, a4.w};
            float bv[4] = {b4.x, b4.y, b4.z, b4.w};
#pragma unroll
            for (int i2 = 0; i2 < 4; ++i2)
#pragma unroll
                for (int j2 = 0; j2 < 4; ++j2)
                    acc[i2][j2] += a[i2] * bv[j2];
        }
        bool diag = (jt == qt);
#pragma unroll
        for (int i2 = 0; i2 < 4; ++i2) {
            int gi = ty * 4 + i2;
            float s[4]; float tm = -1e30f;
#pragma unroll
            for (int j2 = 0; j2 < 4; ++j2) {
                int gj = tx * 4 + j2;
                float vsc = acc[i2][j2] * 0.125f;
                if (diag && gj > gi) vsc = -1e30f;
                s[j2] = vsc;
                tm = fmaxf(tm, vsc);
            }
            float nm = fmaxf(m_t[i2], tm);
            float zadd = 0.f;
#pragma unroll
            for (int j2 = 0; j2 < 4; ++j2)
                zadd += (s[j2] > -1e29f) ? __expf(s[j2] - nm) : 0.f;
            z_t[i2] = z_t[i2] * __expf(m_t[i2] - nm) + zadd;
            m_t[i2] = nm;
        }
    }
#pragma unroll
    for (int i2 = 0; i2 < 4; ++i2) {
        red_m[ty * 4 + i2][tx] = m_t[i2];
        red_z[ty * 4 + i2][tx] = z_t[i2];
    }
    __syncthreads();
    if (tid < 64) {
        float mm = red_m[tid][0];
#pragma unroll
        for (int k = 1; k < 16; ++k) mm = fmaxf(mm, red_m[tid][k]);
        float zz = 0.f;
#pragma unroll
        for (int k = 0; k < 16; ++k) zz += red_z[tid][k] * __expf(red_m[tid][k] - mm);
        mrow[(size_t)bh * T + qt * 64 + tid] = mm;
        zrow[(size_t)bh * T + qt * 64 + tid] = zz;
    }
}

// ---------------- QK^T pass 2: write normalized softmax rows to fp16 c --------
__global__ __launch_bounds__(256) void qk_pass2(const float* __restrict__ qkv,
        const float* __restrict__ mrow, const float* __restrict__ zrow,
        half_t* __restrict__ c_h) {
    int qt = blockIdx.x, h = blockIdx.y, b = blockIdx.z;
    int bh = b * H + h;
    int tid = threadIdx.x, tx = tid & 15, ty = tid >> 4;
    __shared__ __align__(16) float Qs[64][68];
    __shared__ __align__(16) float Ks[64][68];
    const float* qbase = qkv + ((size_t)b * T + qt * 64) * (3 * C) + h * HD;
#pragma unroll
    for (int l = 0; l < 16; ++l) {
        int idx = l * 256 + tid;
        int d = idx & 63, i = idx >> 6;
        Qs[d][i] = qbase[(size_t)i * (3 * C) + d];
    }
    float mI[4], zI[4];
#pragma unroll
    for (int i2 = 0; i2 < 4; ++i2) {
        size_t gr = (size_t)bh * T + qt * 64 + ty * 4 + i2;
        mI[i2] = mrow[gr];
        zI[i2] = 1.f / zrow[gr];
    }
    for (int jt = 0; jt <= qt; ++jt) {
        const float* kbase = qkv + ((size_t)b * T + jt * 64) * (3 * C) + C + h * HD;
        __syncthreads();
#pragma unroll
        for (int l = 0; l < 16; ++l) {
            int idx = l * 256 + tid;
            int d = idx & 63, j = idx >> 6;
            Ks[d][j] = kbase[(size_t)j * (3 * C) + d];
        }
        __syncthreads();
        float acc[4][4] = {};
#pragma unroll 8
        for (int d = 0; d < 64; ++d) {
            float4 a4 = *reinterpret_cast<const float4*>(&Qs[d][ty * 4]);
            float4 b4 = *reinterpret_cast<const float4*>(&Ks[d][tx * 4]);
            float a[4]  = {a4.x, a4.y, a4.z, a4.w};
            float bv[4] = {b4.x, b4.y, b4.z, b4.w};
#pragma unroll
            for (int i2 = 0; i2 < 4; ++i2)
#pragma unroll
                for (int j2 = 0; j2 < 4; ++j2)
                    acc[i2][j2] += a[i2] * bv[j2];
        }
        bool diag = (jt == qt);
#pragma unroll
        for (int i2 = 0; i2 < 4; ++i2) {
            int gi = ty * 4 + i2;
            float cv[4];
#pragma unroll
            for (int j2 = 0; j2 < 4; ++j2) {
                int gj = tx * 4 + j2;
                float vsc = acc[i2][j2] * 0.125f;
                cv[j2] = (diag && gj > gi) ? 0.f : __expf(vsc - mI[i2]) * zI[i2];
            }
            union { __half2 h2[2]; uint2 u; } pk;
            pk.h2[0] = __floats2half2_rn(cv[0], cv[1]);
            pk.h2[1] = __floats2half2_rn(cv[2], cv[3]);
            size_t off = ((size_t)bh * T + qt * 64 + gi) * T + jt * 64 + tx * 4;
            *reinterpret_cast<uint2*>(c_h + off) = pk.u;
        }
    }
}

// ---------------- sinkhorn row pass: u_i = -logT - LSE_j(c_ij + v_j) ----------
__global__ __launch_bounds__(256) void row_u_kernel(const half_t* __restrict__ c,
        const float* __restrict__ v, float* __restrict__ u) {
    int row = blockIdx.x;              // (b*H+h)*T + i
    int bh = row >> 11;                // / T
    int tid = threadIdx.x;
    const half_t* crow = c + (size_t)row * T;
    const float* vrow = v + (size_t)bh * T;
    float4 raw = reinterpret_cast<const float4*>(crow)[tid];   // 8 halves
    const __half2* h2p = reinterpret_cast<const __half2*>(&raw);
    float xs[8];
    float mx = -1e30f;
#pragma unroll
    for (int p = 0; p < 4; ++p) {
        float2 cf = __half22float2(h2p[p]);
        int j = tid * 8 + p * 2;
        xs[p*2]   = cf.x + vrow[j];
        xs[p*2+1] = cf.y + vrow[j + 1];
        mx = fmaxf(mx, fmaxf(xs[p*2], xs[p*2+1]));
    }
    float Mx = block_reduce_max(mx);
    float sum = 0.f;
#pragma unroll
    for (int k = 0; k < 8; ++k) sum += __expf(xs[k] - Mx);
    float S = block_reduce_sum(sum);
    if (tid == 0) u[row] = -LOGT - (Mx + logf(S));
}

// ---------------- sinkhorn col pass: partial sums of exp(c_ij + u_i) ----------
__global__ __launch_bounds__(256) void col_accum_kernel(const half_t* __restrict__ c,
        const float* __restrict__ u, float* __restrict__ acc) {
    int j  = blockIdx.x * 256 + threadIdx.x;
    int r0 = blockIdx.y * 128;
    int bh = blockIdx.z;
    const half_t* cb = c + (size_t)bh * T * T;
    const float* ub = u + (size_t)bh * T;
    float a = 0.f;
#pragma unroll 4
    for (int r = 0; r < 128; ++r)
        a += __expf(__half2float(cb[(size_t)(r0 + r) * T + j]) + ub[r0 + r]);
    atomicAdd(&acc[(size_t)bh * T + j], a);
}

__global__ __launch_bounds__(256) void v_finalize_kernel(const float* __restrict__ acc,
        float* __restrict__ v) {
    int idx = blockIdx.x * 256 + threadIdx.x;
    v[idx] = -LOGT - logf(acc[idx]);
}

// ---------------- y = (exp(c+u+v)*T) @ V, tiled 64x64, f16 out ----------------
__global__ __launch_bounds__(256) void pv_tiled(const half_t* __restrict__ c_h,
        const float* __restrict__ u, const float* __restrict__ v,
        const float* __restrict__ qkv, _Float16* __restrict__ y) {
    int qt = blockIdx.x, h = blockIdx.y, b = blockIdx.z;
    int bh = b * H + h;
    int tid = threadIdx.x, tx = tid & 15, ty = tid >> 4;
    __shared__ __align__(16) float Ps[64][68];   // Ps[j][i]
    __shared__ __align__(16) float Vs[64][68];   // Vs[j][d]
    __shared__ float us[64];
    __shared__ float vs[64];
    if (tid < 64) us[tid] = u[(size_t)bh * T + qt * 64 + tid];
    float acc[4][4] = {};
    const half_t* crow0 = c_h + ((size_t)bh * T + qt * 64) * T;
    for (int jt = 0; jt < T / 64; ++jt) {
        __syncthreads();
        if (tid < 64) vs[tid] = v[(size_t)bh * T + jt * 64 + tid];
        __syncthreads();
#pragma unroll
        for (int l = 0; l < 16; ++l) {
            int idx = l * 256 + tid;
            int j = idx & 63, i = idx >> 6;
            float cc = __half2float(crow0[(size_t)i * T + jt * 64 + j]);
            Ps[j][i] = __expf(cc + us[i] + vs[j]);
        }
        const float* vbase = qkv + ((size_t)b * T + jt * 64) * (3 * C) + 2 * C + h * HD;
#pragma unroll
        for (int l = 0; l < 16; ++l) {
            int idx = l * 256 + tid;
            int d = idx & 63, j = idx >> 6;
            Vs[j][d] = vbase[(size_t)j * (3 * C) + d];
        }
        __syncthreads();
#pragma unroll 8
        for (int j = 0; j < 64; ++j) {
            float4 a4 = *reinterpret_cast<const float4*>(&Ps[j][ty * 4]);
            float4 b4 = *reinterpret_cast<const float4*>(&Vs[j][tx * 4]);
            float a[4]  = {a4.x, a4.y, a4.z, a4.w};
            float bv[4] = {b4.x, b4.y, b4.z, b4.w};
#pragma unroll
            for (int i2 = 0; i2 < 4; ++i2)
#pragma unroll
                for (int j2 = 0; j2 < 4; ++j2)
                    acc[i2][j2] += a[i2] * bv[j2];
        }
    }
#pragma unroll
    for (int i2 = 0; i2 < 4; ++i2)
#pragma unroll
        for (int j2 = 0; j2 < 4; ++j2)
            y[((size_t)b * T + qt * 64 + ty * 4 + i2) * C + h * HD + tx * 4 + j2]
                = (_Float16)(acc[i2][j2] * 2048.f);
}

// -----------------------------------------------------------------------------
extern "C" void kernel_launch(void* const* d_in, const int* in_sizes, int n_in,
                              void* d_out, int out_size, void* d_ws, size_t ws_size,
                              hipStream_t stream) {
    (void)in_sizes; (void)n_in; (void)out_size;
    const float* x      = (const float*)d_in[0];
    const float* t      = (const float*)d_in[1];
    const float* ln1_w  = (const float*)d_in[2];
    const float* ln1_b  = (const float*)d_in[3];
    const float* attn_w = (const float*)d_in[4];
    const float* attn_b = (const float*)d_in[5];
    const float* proj_w = (const float*)d_in[6];
    const float* proj_b = (const float*)d_in[7];
    const float* ln2_w  = (const float*)d_in[8];
    const float* ln2_b  = (const float*)d_in[9];
    const float* fc_w   = (const float*)d_in[10];
    const float* fc_b   = (const float*)d_in[11];
    const float* fc2_w  = (const float*)d_in[12];
    const float* fc2_b  = (const float*)d_in[13];
    float* out = (float*)d_out;

    // ---- workspace layout (124,715,008 bytes) ----
    if (ws_size < 124715008ull) return;   // guard
    char* wsb = (char*)d_ws;
    half_t*    c_h  = (half_t*)wsb;                         // 100,663,296
    float*     qkvb = (float*)(wsb + 100663296ull);         // 18,874,368 (4096×1152 f32)
    _Float16*  xh   = (_Float16*)(wsb + 119537664ull);      //  3,407,872 (4096×416 f16)
    _Float16*  wbuf = (_Float16*)(wsb + 122945536ull);      //  1,277,952 (time-shared Wt)
    float*     u    = (float*)(wsb + 124223488ull);
    float*     vv   = u    + BHT;
    float*     cacc = vv   + BHT;
    float*     mrow = cacc + BHT;
    float*     zrow = mrow + BHT;
    // aliases:
    _Float16* xn_h = xh;               // ln1 -> qkv gemm
    _Float16* yb_h = xh;               // pv -> proj  (xn dead)
    _Float16* hn_h = xh;               // ln2 -> fc   (yb dead)
    float*    hb   = qkvb;             // proj out    (qkv dead after pv)
    _Float16* mb_h = (_Float16*)wsb;   // fc out      (c dead after pv)

    const int M = B * T;  // 4096
    const int KP1 = 416;  // (C+1) padded to 32

    // zero c (fp16) -- upper-triangular tiles stay exactly zero
    zero4_kernel<<<24576, 256, 0, stream>>>((uint4*)c_h);

    // ---- attention sub-block ----
    addtime_ln_f16<<<M, 256, 0, stream>>>(x, t, ln1_w, ln1_b, xn_h, KP1);
    convtrans_kernel<<<dim3(KP1/32, (3*C)/32), 256, 0, stream>>>(attn_w, wbuf, C+1, 3*C, KP1);
    mfma_gemm<0, float><<<dim3(3*C/64, M/64), 256, 0, stream>>>(
        xn_h, wbuf, attn_b, qkvb, M, 3*C, KP1);
    qk_pass1<<<dim3(T/64, H, B), 256, 0, stream>>>(qkvb, mrow, zrow);
    qk_pass2<<<dim3(T/64, H, B), 256, 0, stream>>>(qkvb, mrow, zrow, c_h);

    // ---- sinkhorn: u at iters 0,2,4; v at iters 1,3,5 ----
    zerof_kernel<<<BHT/256, 256, 0, stream>>>(vv);
    row_u_kernel<<<BHT, 256, 0, stream>>>(c_h, vv, u);                     // iter 0
    for (int it = 0; it < 3; ++it) {
        zerof_kernel<<<BHT/256, 256, 0, stream>>>(cacc);
        col_accum_kernel<<<dim3(T/256, T/128, B*H), 256, 0, stream>>>(c_h, u, cacc);
        v_finalize_kernel<<<BHT/256, 256, 0, stream>>>(cacc, vv);          // 1,3,5
        if (it < 2)
            row_u_kernel<<<BHT, 256, 0, stream>>>(c_h, vv, u);             // 2,4
    }

    pv_tiled<<<dim3(T/64, H, B), 256, 0, stream>>>(c_h, u, vv, qkvb, yb_h);
    convtrans_kernel<<<dim3(C/32, C/32), 256, 0, stream>>>(proj_w, wbuf, C, C, C);
    mfma_gemm<0, float><<<dim3(C/64, M/64), 256, 0, stream>>>(
        yb_h, wbuf, proj_b, hb, M, C, C);

    // ---- MLP sub-block ----
    addtime_ln_f16<<<M, 256, 0, stream>>>(hb, t, ln2_w, ln2_b, hn_h, KP1);
    convtrans_kernel<<<dim3(KP1/32, (4*C)/32), 256, 0, stream>>>(fc_w, wbuf, C+1, 4*C, KP1);
    mfma_gemm<1, _Float16><<<dim3(4*C/64, M/64), 256, 0, stream>>>(
        hn_h, wbuf, fc_b, mb_h, M, 4*C, KP1);
    convtrans_kernel<<<dim3((4*C)/32, C/32), 256, 0, stream>>>(fc2_w, wbuf, 4*C, C, 4*C);
    mfma_gemm<0, float><<<dim3(C/64, M/64), 256, 0, stream>>>(
        mb_h, wbuf, fc2_b, out, M, C, 4*C);
}

// Round 4
// 644.958 us; speedup vs baseline: 1.7157x; 1.1748x over previous
//
#include <hip/hip_runtime.h>
#include <hip/hip_fp16.h>
#include <math.h>

#define B 2
#define T 2048
#define C 384
#define H 6
#define HD 64
#define BHT (B*H*T)                    // 24576
#define LOGT 7.6246189861593985f       // log(2048)

typedef __half half_t;
typedef _Float16 f16x8 __attribute__((ext_vector_type(8)));
typedef float f32x4 __attribute__((ext_vector_type(4)));

// ---------------- block reduction helper (256 threads = 4 waves) --------------
__device__ __forceinline__ float block_reduce_sum(float v) {
    __shared__ float sm[4];
    int lane = threadIdx.x & 63, wid = threadIdx.x >> 6;
#pragma unroll
    for (int o = 32; o > 0; o >>= 1) v += __shfl_down(v, o, 64);
    __syncthreads();
    if (lane == 0) sm[wid] = v;
    __syncthreads();
    return sm[0] + sm[1] + sm[2] + sm[3];
}

__global__ __launch_bounds__(256) void zerof_kernel(float* __restrict__ p) {
    p[(size_t)blockIdx.x * 256 + threadIdx.x] = 0.f;
}

// ---------------- add_time + layernorm -> f16 rows (stride KP, zero-padded) ---
__global__ __launch_bounds__(256) void addtime_ln_f16(
        const float* __restrict__ src, const float* __restrict__ tptr,
        const float* __restrict__ w, const float* __restrict__ bb,
        _Float16* __restrict__ dst, int KP) {
    const int n = C + 1;               // 385
    int row = blockIdx.x;              // over B*T
    const float* srow = src + (size_t)row * C;
    float tval = tptr[0];
    int i0 = threadIdx.x;
    int i1 = threadIdx.x + 256;
    float v0 = srow[i0];
    bool has1 = (i1 < n);
    float v1 = 0.f;
    if (has1) v1 = (i1 < C) ? srow[i1] : tval;
    float s  = block_reduce_sum(v0 + v1);
    float sq = block_reduce_sum(v0*v0 + v1*v1);
    float mean = s / n;
    float var  = sq / n - mean * mean;
    float rstd = rsqrtf(var + 1e-5f);
    _Float16* drow = dst + (size_t)row * KP;
    drow[i0] = (_Float16)((v0 - mean) * rstd * w[i0] + bb[i0]);
    if (has1) drow[i1] = (_Float16)((v1 - mean) * rstd * w[i1] + bb[i1]);
    else if (i1 < KP) drow[i1] = (_Float16)0.f;
}

// ------- weight convert+transpose: W (K×N fp32) -> Wt (N×KP f16, zero-pad) ----
__global__ __launch_bounds__(256) void convtrans_kernel(const float* __restrict__ W,
        _Float16* __restrict__ Wt, int K, int N, int KP) {
    __shared__ float tile[32][33];
    int k0 = blockIdx.x * 32, n0 = blockIdx.y * 32;
    int tx = threadIdx.x & 31, ty = threadIdx.x >> 5;
#pragma unroll
    for (int i = 0; i < 4; ++i) {
        int k = k0 + ty + i * 8, n = n0 + tx;
        tile[ty + i * 8][tx] = (k < K && n < N) ? W[(size_t)k * N + n] : 0.f;
    }
    __syncthreads();
#pragma unroll
    for (int i = 0; i < 4; ++i) {
        int n = n0 + ty + i * 8, k = k0 + tx;
        if (n < N && k < KP) Wt[(size_t)n * KP + k] = (_Float16)tile[tx][ty + i * 8];
    }
}

// ---------------- f16 MFMA GEMM: out = A(M×KP) @ Wt(N×KP)^T + bias ------------
template<int ACT, typename OUT_T>
__global__ __launch_bounds__(256) void mfma_gemm(
        const _Float16* __restrict__ A, const _Float16* __restrict__ Wt,
        const float* __restrict__ bias, OUT_T* __restrict__ out,
        int M, int N, int KP) {
    __shared__ __align__(16) _Float16 As[64][40];
    __shared__ __align__(16) _Float16 Bs[64][40];
    int tid = threadIdx.x;
    int lane = tid & 63, wave = tid >> 6;
    int wr = wave >> 1, wc = wave & 1;
    int m0 = blockIdx.y * 64, n0 = blockIdx.x * 64;
    int arow = tid >> 2, seg = tid & 3;
    int lrow = lane & 15, lseg = lane >> 4;
    f32x4 acc[2][2] = {};
    for (int k0 = 0; k0 < KP; k0 += 32) {
        __syncthreads();
        *(f16x8*)&As[arow][seg * 8] =
            *(const f16x8*)&A[(size_t)(m0 + arow) * KP + k0 + seg * 8];
        *(f16x8*)&Bs[arow][seg * 8] =
            *(const f16x8*)&Wt[(size_t)(n0 + arow) * KP + k0 + seg * 8];
        __syncthreads();
        f16x8 af[2], bf[2];
#pragma unroll
        for (int i = 0; i < 2; ++i)
            af[i] = *(const f16x8*)&As[wr * 32 + i * 16 + lrow][lseg * 8];
#pragma unroll
        for (int j = 0; j < 2; ++j)
            bf[j] = *(const f16x8*)&Bs[wc * 32 + j * 16 + lrow][lseg * 8];
#pragma unroll
        for (int i = 0; i < 2; ++i)
#pragma unroll
            for (int j = 0; j < 2; ++j)
                acc[i][j] = __builtin_amdgcn_mfma_f32_16x16x32_f16(
                    af[i], bf[j], acc[i][j], 0, 0, 0);
    }
    int lcol = lane & 15, lr4 = (lane >> 4) * 4;
#pragma unroll
    for (int i = 0; i < 2; ++i)
#pragma unroll
        for (int j = 0; j < 2; ++j) {
            int col = n0 + wc * 32 + j * 16 + lcol;
            float bv = bias[col];
#pragma unroll
            for (int r = 0; r < 4; ++r) {
                int row = m0 + wr * 32 + i * 16 + lr4 + r;
                float v = acc[i][j][r] + bv;
                if (ACT == 1) v = 0.5f * v * (1.f + erff(v * 0.70710678118654752f));
                out[(size_t)row * N + col] = (OUT_T)v;
            }
        }
}

// ---------------- stage 64×64 fp32 (row stride 3C) -> f16 LDS [64][72] --------
__device__ __forceinline__ void stage64(const float* __restrict__ base,
        _Float16 (*dst)[72], int tid) {
#pragma unroll
    for (int l = 0; l < 16; ++l) {
        int idx = l * 256 + tid;
        int d = idx & 63, r = idx >> 6;
        dst[r][d] = (_Float16)base[(size_t)r * (3 * C) + d];
    }
}

// ---------------- qk pass1: z_i = sum_{j<=i} exp(s_ij)  (max-free) ------------
__global__ __launch_bounds__(256) void qk1_mfma(const float* __restrict__ qkv,
        float* __restrict__ zrow) {
    int qt = blockIdx.x, h = blockIdx.y, b = blockIdx.z;
    int bh = b * H + h;
    int tid = threadIdx.x, lane = tid & 63, wave = tid >> 6;
    int wr = wave >> 1, wc = wave & 1;
    int lrow = lane & 15, lseg = lane >> 4;
    int orow = (lane >> 4) * 4, ocol = lane & 15;
    __shared__ __align__(16) _Float16 Qs[64][72];
    __shared__ __align__(16) _Float16 Ks[64][72];
    __shared__ float zred[64][2];
    stage64(qkv + ((size_t)b*T + qt*64)*(3*C) + h*HD, Qs, tid);
    float z_t[2][4] = {};
    const f32x4 zero4v = {0.f, 0.f, 0.f, 0.f};
    for (int jt = 0; jt <= qt; ++jt) {
        __syncthreads();
        stage64(qkv + ((size_t)b*T + jt*64)*(3*C) + C + h*HD, Ks, tid);
        __syncthreads();
        f32x4 acc[2][2];
        {
            f16x8 af[2], bf[2];
#pragma unroll
            for (int i = 0; i < 2; ++i) af[i] = *(const f16x8*)&Qs[wr*32+i*16+lrow][lseg*8];
#pragma unroll
            for (int j = 0; j < 2; ++j) bf[j] = *(const f16x8*)&Ks[wc*32+j*16+lrow][lseg*8];
#pragma unroll
            for (int i = 0; i < 2; ++i)
#pragma unroll
                for (int j = 0; j < 2; ++j)
                    acc[i][j] = __builtin_amdgcn_mfma_f32_16x16x32_f16(af[i], bf[j], zero4v, 0,0,0);
#pragma unroll
            for (int i = 0; i < 2; ++i) af[i] = *(const f16x8*)&Qs[wr*32+i*16+lrow][32+lseg*8];
#pragma unroll
            for (int j = 0; j < 2; ++j) bf[j] = *(const f16x8*)&Ks[wc*32+j*16+lrow][32+lseg*8];
#pragma unroll
            for (int i = 0; i < 2; ++i)
#pragma unroll
                for (int j = 0; j < 2; ++j)
                    acc[i][j] = __builtin_amdgcn_mfma_f32_16x16x32_f16(af[i], bf[j], acc[i][j], 0,0,0);
        }
        bool diag = (jt == qt);
#pragma unroll
        for (int i = 0; i < 2; ++i)
#pragma unroll
            for (int r = 0; r < 4; ++r) {
                int rl = wr*32 + i*16 + orow + r;
#pragma unroll
                for (int j = 0; j < 2; ++j) {
                    int cl = wc*32 + j*16 + ocol;
                    float s = acc[i][j][r] * 0.125f;
                    if (diag && cl > rl) s = -1e30f;
                    z_t[i][r] += __expf(s);
                }
            }
    }
#pragma unroll
    for (int i = 0; i < 2; ++i)
#pragma unroll
        for (int r = 0; r < 4; ++r) {
            float zz = z_t[i][r];
            zz += __shfl_xor(zz, 1, 64);
            zz += __shfl_xor(zz, 2, 64);
            zz += __shfl_xor(zz, 4, 64);
            zz += __shfl_xor(zz, 8, 64);
            z_t[i][r] = zz;
        }
    __syncthreads();
    if (ocol == 0) {
#pragma unroll
        for (int i = 0; i < 2; ++i)
#pragma unroll
            for (int r = 0; r < 4; ++r)
                zred[wr*32 + i*16 + orow + r][wc] = z_t[i][r];
    }
    __syncthreads();
    if (tid < 64)
        zrow[(size_t)bh*T + qt*64 + tid] = zred[tid][0] + zred[tid][1];
}

// ------- qk pass2: write normalized c (f16) + fold u0 = -logT - log(sum exp c)
__global__ __launch_bounds__(256) void qk2_mfma(const float* __restrict__ qkv,
        const float* __restrict__ zrow, half_t* __restrict__ c_h,
        float* __restrict__ u) {
    int qt = blockIdx.x, h = blockIdx.y, b = blockIdx.z;
    int bh = b * H + h;
    int tid = threadIdx.x, lane = tid & 63, wave = tid >> 6;
    int wr = wave >> 1, wc = wave & 1;
    int lrow = lane & 15, lseg = lane >> 4;
    int orow = (lane >> 4) * 4, ocol = lane & 15;
    __shared__ __align__(16) _Float16 Qs[64][72];
    __shared__ __align__(16) _Float16 Ks[64][72];
    __shared__ __align__(16) _Float16 Pst[64][72];
    __shared__ float invzs[64];
    __shared__ float sred[64][2];
    stage64(qkv + ((size_t)b*T + qt*64)*(3*C) + h*HD, Qs, tid);
    if (tid < 64) invzs[tid] = 1.f / zrow[(size_t)bh*T + qt*64 + tid];
    float S_t[2][4] = {};
    const f32x4 zero4v = {0.f, 0.f, 0.f, 0.f};
    half_t* cbase = c_h + ((size_t)bh*T + qt*64)*T;
    for (int jt = 0; jt <= qt; ++jt) {
        __syncthreads();
        stage64(qkv + ((size_t)b*T + jt*64)*(3*C) + C + h*HD, Ks, tid);
        __syncthreads();
        f32x4 acc[2][2];
        {
            f16x8 af[2], bf[2];
#pragma unroll
            for (int i = 0; i < 2; ++i) af[i] = *(const f16x8*)&Qs[wr*32+i*16+lrow][lseg*8];
#pragma unroll
            for (int j = 0; j < 2; ++j) bf[j] = *(const f16x8*)&Ks[wc*32+j*16+lrow][lseg*8];
#pragma unroll
            for (int i = 0; i < 2; ++i)
#pragma unroll
                for (int j = 0; j < 2; ++j)
                    acc[i][j] = __builtin_amdgcn_mfma_f32_16x16x32_f16(af[i], bf[j], zero4v, 0,0,0);
#pragma unroll
            for (int i = 0; i < 2; ++i) af[i] = *(const f16x8*)&Qs[wr*32+i*16+lrow][32+lseg*8];
#pragma unroll
            for (int j = 0; j < 2; ++j) bf[j] = *(const f16x8*)&Ks[wc*32+j*16+lrow][32+lseg*8];
#pragma unroll
            for (int i = 0; i < 2; ++i)
#pragma unroll
                for (int j = 0; j < 2; ++j)
                    acc[i][j] = __builtin_amdgcn_mfma_f32_16x16x32_f16(af[i], bf[j], acc[i][j], 0,0,0);
        }
        bool diag = (jt == qt);
#pragma unroll
        for (int i = 0; i < 2; ++i)
#pragma unroll
            for (int r = 0; r < 4; ++r) {
                int rl = wr*32 + i*16 + orow + r;
                float invz = invzs[rl];
#pragma unroll
                for (int j = 0; j < 2; ++j) {
                    int cl = wc*32 + j*16 + ocol;
                    float s = acc[i][j][r] * 0.125f;
                    if (diag && cl > rl) s = -1e30f;
                    float p = __expf(s) * invz;          // masked -> 0
                    bool inc = !diag || (cl <= rl);
                    S_t[i][r] += inc ? __expf(p) : 0.f;
                    Pst[rl][cl] = (_Float16)p;
                }
            }
        __syncthreads();
        half_t* cdst = cbase + jt*64;
#pragma unroll
        for (int k = 0; k < 2; ++k) {
            int idx = k*256 + tid;
            int rr = idx >> 3, cg8 = (idx & 7) * 8;
            *(uint4*)&cdst[(size_t)rr*T + cg8] = *(const uint4*)&Pst[rr][cg8];
        }
    }
#pragma unroll
    for (int i = 0; i < 2; ++i)
#pragma unroll
        for (int r = 0; r < 4; ++r) {
            float zz = S_t[i][r];
            zz += __shfl_xor(zz, 1, 64);
            zz += __shfl_xor(zz, 2, 64);
            zz += __shfl_xor(zz, 4, 64);
            zz += __shfl_xor(zz, 8, 64);
            S_t[i][r] = zz;
        }
    __syncthreads();
    if (ocol == 0) {
#pragma unroll
        for (int i = 0; i < 2; ++i)
#pragma unroll
            for (int r = 0; r < 4; ++r)
                sred[wr*32 + i*16 + orow + r][wc] = S_t[i][r];
    }
    __syncthreads();
    if (tid < 64) {
        int ig = qt*64 + tid;
        float S = sred[tid][0] + sred[tid][1];
        u[(size_t)bh*T + ig] = -LOGT - logf(S + (float)(T - 1 - ig));
    }
}

// --------- scan: dst[bh*33+kt] = prefix/suffix tile sums of exp(src) ----------
template<int SUFFIX>
__global__ __launch_bounds__(256) void scan_exp_kernel(const float* __restrict__ src,
        float* __restrict__ dst) {
    int bh = blockIdx.x;
    int tid = threadIdx.x;
    __shared__ float part[256];
    __shared__ float ts[32];
    const float* s = src + (size_t)bh * T;
    float a = 0.f;
#pragma unroll
    for (int e = 0; e < 8; ++e) a += __expf(s[tid*8 + e]);
    part[tid] = a;
    __syncthreads();
    if (tid < 32) {
        float t0 = 0.f;
#pragma unroll
        for (int k = 0; k < 8; ++k) t0 += part[tid*8 + k];
        ts[tid] = t0;
    }
    __syncthreads();
    if (tid == 0) {
        if (SUFFIX) {
            float run = 0.f;
            dst[bh*33 + 32] = 0.f;
            for (int kt = 31; kt >= 0; --kt) { run += ts[kt]; dst[bh*33+kt] = run; }
        } else {
            float run = 0.f;
            for (int kt = 0; kt < 33; ++kt) { dst[bh*33+kt] = run; if (kt < 32) run += ts[kt]; }
        }
    }
}

// ---------------- col pass (causal): acc_j += sum_{r>=j&~63} exp(c_rj+u_r) ----
__global__ __launch_bounds__(256) void col_accum_causal(const half_t* __restrict__ c,
        const float* __restrict__ u, float* __restrict__ acc) {
    int jb = blockIdx.x * 256;
    int r0 = blockIdx.y * 128;
    int bh = blockIdx.z;
    if (r0 + 128 <= jb) return;
    int tid = threadIdx.x;
    int j = jb + tid;
    int rstart = r0, wtile = jb + (tid & ~63);
    if (wtile > rstart) rstart = wtile;      // wave-uniform
    int rend = r0 + 128;
    const half_t* cb = c + (size_t)bh * T * T;
    const float* ub = u + (size_t)bh * T;
    float a = 0.f;
    for (int r = rstart; r < rend; ++r)
        a += __expf(__half2float(cb[(size_t)r * T + j]) + ub[r]);
    if (rstart < rend) atomicAdd(&acc[(size_t)bh * T + j], a);
}

__global__ __launch_bounds__(256) void v_finalize2(const float* __restrict__ acc,
        const float* __restrict__ peu, float* __restrict__ v) {
    int idx = blockIdx.x * 256 + threadIdx.x;
    int bh = idx >> 11, j = idx & 2047;
    v[idx] = -LOGT - logf(acc[idx] + peu[bh*33 + (j >> 6)]);
}

// ---------------- row pass (causal): u_i = -logT - log(sum + Sev tail) --------
__global__ __launch_bounds__(256) void row_u_causal(const half_t* __restrict__ c,
        const float* __restrict__ v, const float* __restrict__ sev,
        float* __restrict__ u) {
    int row = blockIdx.x;              // bh*T + i
    int bh = row >> 11;
    int i = row & 2047;
    int qt = i >> 6;
    int nread = (qt + 1) << 6;
    int tid = threadIdx.x;
    const half_t* crow = c + (size_t)row * T;
    const float* vrow = v + (size_t)bh * T;
    float sum = 0.f;
    if (tid * 8 < nread) {
        uint4 raw = *(const uint4*)(crow + tid*8);
        const __half2* h2 = (const __half2*)&raw;
#pragma unroll
        for (int p = 0; p < 4; ++p) {
            float2 cf = __half22float2(h2[p]);
            sum += __expf(cf.x + vrow[tid*8 + p*2]);
            sum += __expf(cf.y + vrow[tid*8 + p*2 + 1]);
        }
    }
    float S = block_reduce_sum(sum);
    if (tid == 0) u[row] = -LOGT - logf(S + sev[bh*33 + qt + 1]);
}

// ---------------- Wsuf[kt][d] = sum_{tiles jt>=kt} sum_j exp(v_j) V[j][d] -----
__global__ __launch_bounds__(256) void wv_suffix_kernel(const float* __restrict__ qkv,
        const float* __restrict__ v, float* __restrict__ wsuf) {
    int bh = blockIdx.x;
    int b = bh / H, h = bh % H;
    int tid = threadIdx.x;
    int d = tid & 63, g = tid >> 6;
    __shared__ float evs[2048];
    __shared__ float W[32][64];
    __shared__ float red[4][64];
    const float* vb = v + (size_t)bh * T;
#pragma unroll
    for (int k = 0; k < 8; ++k) evs[tid + k*256] = __expf(vb[tid + k*256]);
    __syncthreads();
    const float* vbase = qkv + (size_t)b * T * (3*C) + 2*C + h*HD + d;
    for (int jt = 0; jt < 32; ++jt) {
        float a = 0.f;
#pragma unroll
        for (int jj = 0; jj < 16; ++jj) {
            int j = jt*64 + g*16 + jj;
            a += evs[j] * vbase[(size_t)j * (3*C)];
        }
        red[g][d] = a;
        __syncthreads();
        if (g == 0) W[jt][d] = red[0][d] + red[1][d] + red[2][d] + red[3][d];
        __syncthreads();
    }
    if (tid < 64) {
        float run = 0.f;
        wsuf[((size_t)bh*33 + 32)*64 + tid] = 0.f;
        for (int kt = 31; kt >= 0; --kt) {
            run += W[kt][tid];
            wsuf[((size_t)bh*33 + kt)*64 + tid] = run;
        }
    }
}

// ---------------- pv: y = (exp(c+u+v+logT)) @ V  (MFMA, causal+tail) ----------
__global__ __launch_bounds__(256) void pv_mfma(const half_t* __restrict__ c_h,
        const float* __restrict__ u, const float* __restrict__ v,
        const float* __restrict__ qkv, const float* __restrict__ wsuf,
        _Float16* __restrict__ y) {
    int qt = blockIdx.x, h = blockIdx.y, b = blockIdx.z;
    int bh = b * H + h;
    int tid = threadIdx.x, lane = tid & 63, wave = tid >> 6;
    int wr = wave >> 1, wc = wave & 1;
    int lrow = lane & 15, lseg = lane >> 4;
    int orow = (lane >> 4) * 4, ocol = lane & 15;
    __shared__ __align__(16) _Float16 Ps[64][72];
    __shared__ __align__(16) _Float16 Vt[64][72];
    __shared__ float us[64], eus[64], wsf[64], vs[64];
    if (tid < 64) {
        float uu = u[(size_t)bh*T + qt*64 + tid] + LOGT;
        us[tid] = uu;
        eus[tid] = __expf(uu);
        wsf[tid] = wsuf[((size_t)bh*33 + qt + 1)*64 + tid];
    }
    f32x4 acc[2][2] = {};
    const half_t* crow0 = c_h + ((size_t)bh*T + qt*64)*T;
    int dv = tid & 63, gv = tid >> 6;
    const float* vbase = qkv + (size_t)b * T * (3*C) + 2*C + h*HD + dv;
    for (int jt = 0; jt <= qt; ++jt) {
        __syncthreads();
        if (tid < 64) vs[tid] = v[(size_t)bh*T + jt*64 + tid];
        __syncthreads();
        // stage P = exp(c + u + v + logT) as f16
#pragma unroll
        for (int k = 0; k < 2; ++k) {
            int idx = k*256 + tid;
            int rr = idx >> 3, j8 = (idx & 7) * 8;
            uint4 raw = *(const uint4*)&crow0[(size_t)rr*T + jt*64 + j8];
            const __half2* h2 = (const __half2*)&raw;
            f16x8 p8;
#pragma unroll
            for (int p = 0; p < 4; ++p) {
                float2 cf = __half22float2(h2[p]);
                p8[p*2]   = (_Float16)__expf(cf.x + us[rr] + vs[j8 + p*2]);
                p8[p*2+1] = (_Float16)__expf(cf.y + us[rr] + vs[j8 + p*2 + 1]);
            }
            *(f16x8*)&Ps[rr][j8] = p8;
        }
        // stage V^T (reg-staged transpose, 16B LDS writes)
#pragma unroll
        for (int k = 0; k < 2; ++k) {
            int jg = (gv + k*4) * 8;
            f16x8 v8;
#pragma unroll
            for (int jj = 0; jj < 8; ++jj)
                v8[jj] = (_Float16)vbase[(size_t)(jt*64 + jg + jj) * (3*C)];
            *(f16x8*)&Vt[dv][jg] = v8;
        }
        __syncthreads();
        f16x8 af[2], bf[2];
#pragma unroll
        for (int i = 0; i < 2; ++i) af[i] = *(const f16x8*)&Ps[wr*32+i*16+lrow][lseg*8];
#pragma unroll
        for (int j = 0; j < 2; ++j) bf[j] = *(const f16x8*)&Vt[wc*32+j*16+lrow][lseg*8];
#pragma unroll
        for (int i = 0; i < 2; ++i)
#pragma unroll
            for (int j = 0; j < 2; ++j)
                acc[i][j] = __builtin_amdgcn_mfma_f32_16x16x32_f16(af[i], bf[j], acc[i][j], 0,0,0);
#pragma unroll
        for (int i = 0; i < 2; ++i) af[i] = *(const f16x8*)&Ps[wr*32+i*16+lrow][32+lseg*8];
#pragma unroll
        for (int j = 0; j < 2; ++j) bf[j] = *(const f16x8*)&Vt[wc*32+j*16+lrow][32+lseg*8];
#pragma unroll
        for (int i = 0; i < 2; ++i)
#pragma unroll
            for (int j = 0; j < 2; ++j)
                acc[i][j] = __builtin_amdgcn_mfma_f32_16x16x32_f16(af[i], bf[j], acc[i][j], 0,0,0);
    }
#pragma unroll
    for (int i = 0; i < 2; ++i)
#pragma unroll
        for (int j = 0; j < 2; ++j)
#pragma unroll
            for (int r = 0; r < 4; ++r) {
                int rl = wr*32 + i*16 + orow + r;
                int cl = wc*32 + j*16 + ocol;
                float val = acc[i][j][r] + eus[rl] * wsf[cl];
                y[((size_t)b*T + qt*64 + rl)*C + h*HD + cl] = (_Float16)val;
            }
}

// -----------------------------------------------------------------------------
extern "C" void kernel_launch(void* const* d_in, const int* in_sizes, int n_in,
                              void* d_out, int out_size, void* d_ws, size_t ws_size,
                              hipStream_t stream) {
    (void)in_sizes; (void)n_in; (void)out_size;
    const float* x      = (const float*)d_in[0];
    const float* t      = (const float*)d_in[1];
    const float* ln1_w  = (const float*)d_in[2];
    const float* ln1_b  = (const float*)d_in[3];
    const float* attn_w = (const float*)d_in[4];
    const float* attn_b = (const float*)d_in[5];
    const float* proj_w = (const float*)d_in[6];
    const float* proj_b = (const float*)d_in[7];
    const float* ln2_w  = (const float*)d_in[8];
    const float* ln2_b  = (const float*)d_in[9];
    const float* fc_w   = (const float*)d_in[10];
    const float* fc_b   = (const float*)d_in[11];
    const float* fc2_w  = (const float*)d_in[12];
    const float* fc2_b  = (const float*)d_in[13];
    float* out = (float*)d_out;

    // ---- workspace layout (124,722,176 bytes) ----
    if (ws_size < 124722176ull) return;
    char* wsb = (char*)d_ws;
    half_t*    c_h  = (half_t*)wsb;                         // 100,663,296
    float*     qkvb = (float*)(wsb + 100663296ull);         // 4096×1152 f32
    _Float16*  xh   = (_Float16*)(wsb + 119537664ull);      // 4096×416 f16
    _Float16*  wbuf = (_Float16*)(wsb + 122945536ull);      // time-shared Wt
    float*     u    = (float*)(wsb + 124223488ull);         // BHT
    float*     vv   = u    + BHT;
    float*     cacc = vv   + BHT;
    float*     zrow = cacc + BHT;
    float*     peu  = zrow + BHT;                           // 12×33 (+pad)
    float*     sev  = peu  + 512;
    float*     wsuf = sev  + 512;                           // 12×33×64
    // aliases:
    _Float16* xn_h = xh;
    _Float16* yb_h = xh;
    _Float16* hn_h = xh;
    float*    hb   = qkvb;
    _Float16* mb_h = (_Float16*)wsb;

    const int M = B * T;   // 4096
    const int KP1 = 416;   // (C+1) padded to 32

    // ---- attention sub-block ----
    addtime_ln_f16<<<M, 256, 0, stream>>>(x, t, ln1_w, ln1_b, xn_h, KP1);
    convtrans_kernel<<<dim3(KP1/32, (3*C)/32), 256, 0, stream>>>(attn_w, wbuf, C+1, 3*C, KP1);
    mfma_gemm<0, float><<<dim3(3*C/64, M/64), 256, 0, stream>>>(
        xn_h, wbuf, attn_b, qkvb, M, 3*C, KP1);
    qk1_mfma<<<dim3(T/64, H, B), 256, 0, stream>>>(qkvb, zrow);
    qk2_mfma<<<dim3(T/64, H, B), 256, 0, stream>>>(qkvb, zrow, c_h, u);   // u0

    // ---- sinkhorn iters: v1,u2,v3,u4,v5 (u0 folded above) ----
    scan_exp_kernel<0><<<B*H, 256, 0, stream>>>(u, peu);
    for (int it = 0; it < 3; ++it) {
        zerof_kernel<<<BHT/256, 256, 0, stream>>>(cacc);
        col_accum_causal<<<dim3(T/256, T/128, B*H), 256, 0, stream>>>(c_h, u, cacc);
        v_finalize2<<<BHT/256, 256, 0, stream>>>(cacc, peu, vv);
        if (it < 2) {
            scan_exp_kernel<1><<<B*H, 256, 0, stream>>>(vv, sev);
            row_u_causal<<<BHT, 256, 0, stream>>>(c_h, vv, sev, u);
            scan_exp_kernel<0><<<B*H, 256, 0, stream>>>(u, peu);
        }
    }
    wv_suffix_kernel<<<B*H, 256, 0, stream>>>(qkvb, vv, wsuf);
    pv_mfma<<<dim3(T/64, H, B), 256, 0, stream>>>(c_h, u, vv, qkvb, wsuf, yb_h);

    convtrans_kernel<<<dim3(C/32, C/32), 256, 0, stream>>>(proj_w, wbuf, C, C, C);
    mfma_gemm<0, float><<<dim3(C/64, M/64), 256, 0, stream>>>(
        yb_h, wbuf, proj_b, hb, M, C, C);

    // ---- MLP sub-block ----
    addtime_ln_f16<<<M, 256, 0, stream>>>(hb, t, ln2_w, ln2_b, hn_h, KP1);
    convtrans_kernel<<<dim3(KP1/32, (4*C)/32), 256, 0, stream>>>(fc_w, wbuf, C+1, 4*C, KP1);
    mfma_gemm<1, _Float16><<<dim3(4*C/64, M/64), 256, 0, stream>>>(
        hn_h, wbuf, fc_b, mb_h, M, 4*C, KP1);
    convtrans_kernel<<<dim3((4*C)/32, C/32), 256, 0, stream>>>(fc2_w, wbuf, 4*C, C, 4*C);
    mfma_gemm<0, float><<<dim3(C/64, M/64), 256, 0, stream>>>(
        mb_h, wbuf, fc2_b, out, M, C, 4*C);
}

// Round 6
// 438.258 us; speedup vs baseline: 2.5250x; 1.4716x over previous
//
#include <hip/hip_runtime.h>
#include <hip/hip_fp16.h>
#include <math.h>

#define B 2
#define T 2048
#define C 384
#define H 6
#define HD 64
#define BHT (B*H*T)                    // 24576
#define LOGT 7.6246189861593985f       // log(2048)

typedef __half half_t;
typedef _Float16 f16x8 __attribute__((ext_vector_type(8)));
typedef float f32x4 __attribute__((ext_vector_type(4)));

// ---------------- reduction helpers ------------------------------------------
__device__ __forceinline__ float block_reduce_sum(float v) {
    __shared__ float sm[4];
    int lane = threadIdx.x & 63, wid = threadIdx.x >> 6;
#pragma unroll
    for (int o = 32; o > 0; o >>= 1) v += __shfl_down(v, o, 64);
    __syncthreads();
    if (lane == 0) sm[wid] = v;
    __syncthreads();
    return sm[0] + sm[1] + sm[2] + sm[3];
}

__device__ __forceinline__ float wave_allreduce_sum(float v) {
#pragma unroll
    for (int o = 1; o < 64; o <<= 1) v += __shfl_xor(v, o, 64);
    return v;
}

__global__ __launch_bounds__(256) void zerof_kernel(float* __restrict__ p) {
    p[(size_t)blockIdx.x * 256 + threadIdx.x] = 0.f;
}

// ---------------- add_time + layernorm -> f16 rows (stride KP, zero-padded) ---
__global__ __launch_bounds__(256) void addtime_ln_f16(
        const float* __restrict__ src, const float* __restrict__ tptr,
        const float* __restrict__ w, const float* __restrict__ bb,
        _Float16* __restrict__ dst, int KP) {
    const int n = C + 1;               // 385
    int row = blockIdx.x;              // over B*T
    const float* srow = src + (size_t)row * C;
    float tval = tptr[0];
    int i0 = threadIdx.x;
    int i1 = threadIdx.x + 256;
    float v0 = srow[i0];
    bool has1 = (i1 < n);
    float v1 = 0.f;
    if (has1) v1 = (i1 < C) ? srow[i1] : tval;
    float s  = block_reduce_sum(v0 + v1);
    float sq = block_reduce_sum(v0*v0 + v1*v1);
    float mean = s / n;
    float var  = sq / n - mean * mean;
    float rstd = rsqrtf(var + 1e-5f);
    _Float16* drow = dst + (size_t)row * KP;
    drow[i0] = (_Float16)((v0 - mean) * rstd * w[i0] + bb[i0]);
    if (has1) drow[i1] = (_Float16)((v1 - mean) * rstd * w[i1] + bb[i1]);
    else if (i1 < KP) drow[i1] = (_Float16)0.f;
}

// ------- weight convert+transpose: W (K×N fp32) -> Wt (N×KP f16, zero-pad) ----
__global__ __launch_bounds__(256) void convtrans_kernel(const float* __restrict__ W,
        _Float16* __restrict__ Wt, int K, int N, int KP) {
    __shared__ float tile[32][33];
    int k0 = blockIdx.x * 32, n0 = blockIdx.y * 32;
    int tx = threadIdx.x & 31, ty = threadIdx.x >> 5;
#pragma unroll
    for (int i = 0; i < 4; ++i) {
        int k = k0 + ty + i * 8, n = n0 + tx;
        tile[ty + i * 8][tx] = (k < K && n < N) ? W[(size_t)k * N + n] : 0.f;
    }
    __syncthreads();
#pragma unroll
    for (int i = 0; i < 4; ++i) {
        int n = n0 + ty + i * 8, k = k0 + tx;
        if (n < N && k < KP) Wt[(size_t)n * KP + k] = (_Float16)tile[tx][ty + i * 8];
    }
}

// ---------------- LDS A-stage loaders (f16 or f32 source) ---------------------
__device__ __forceinline__ f16x8 load8(const _Float16* p) { return *(const f16x8*)p; }
__device__ __forceinline__ f16x8 load8(const float* p) {
    float4 a = *(const float4*)p, b2 = *(const float4*)(p + 4);
    f16x8 r;
    r[0]=(_Float16)a.x; r[1]=(_Float16)a.y; r[2]=(_Float16)a.z; r[3]=(_Float16)a.w;
    r[4]=(_Float16)b2.x; r[5]=(_Float16)b2.y; r[6]=(_Float16)b2.z; r[7]=(_Float16)b2.w;
    return r;
}

// ---------------- f16 MFMA GEMM: out = A(M×KP) @ Wt(N×KP)^T + bias ------------
// ACT: 0 none, 1 exact gelu.  QKV: 1 => write f16 head-major q/k/v layout.
template<int ACT, int QKV, typename AT, typename OUT_T>
__global__ __launch_bounds__(256) void mfma_gemm(
        const AT* __restrict__ A, const _Float16* __restrict__ Wt,
        const float* __restrict__ bias, OUT_T* __restrict__ out,
        int M, int N, int KP) {
    __shared__ __align__(16) _Float16 As[64][40];
    __shared__ __align__(16) _Float16 Bs[64][40];
    int tid = threadIdx.x;
    int lane = tid & 63, wave = tid >> 6;
    int wr = wave >> 1, wc = wave & 1;
    int m0 = blockIdx.y * 64, n0 = blockIdx.x * 64;
    int arow = tid >> 2, seg = tid & 3;
    int lrow = lane & 15, lseg = lane >> 4;
    f32x4 acc[2][2] = {};
    for (int k0 = 0; k0 < KP; k0 += 32) {
        __syncthreads();
        *(f16x8*)&As[arow][seg * 8] = load8(&A[(size_t)(m0 + arow) * KP + k0 + seg * 8]);
        *(f16x8*)&Bs[arow][seg * 8] = *(const f16x8*)&Wt[(size_t)(n0 + arow) * KP + k0 + seg * 8];
        __syncthreads();
        f16x8 af[2], bf[2];
#pragma unroll
        for (int i = 0; i < 2; ++i) af[i] = *(const f16x8*)&As[wr*32 + i*16 + lrow][lseg*8];
#pragma unroll
        for (int j = 0; j < 2; ++j) bf[j] = *(const f16x8*)&Bs[wc*32 + j*16 + lrow][lseg*8];
#pragma unroll
        for (int i = 0; i < 2; ++i)
#pragma unroll
            for (int j = 0; j < 2; ++j)
                acc[i][j] = __builtin_amdgcn_mfma_f32_16x16x32_f16(af[i], bf[j], acc[i][j], 0, 0, 0);
    }
    int lcol = lane & 15, lr4 = (lane >> 4) * 4;
#pragma unroll
    for (int i = 0; i < 2; ++i)
#pragma unroll
        for (int j = 0; j < 2; ++j) {
            int col = n0 + wc * 32 + j * 16 + lcol;
            float bv = bias[col];
#pragma unroll
            for (int r = 0; r < 4; ++r) {
                int row = m0 + wr * 32 + i * 16 + lr4 + r;
                float v = acc[i][j][r] + bv;
                if (ACT == 1) v = 0.5f * v * (1.f + erff(v * 0.70710678118654752f));
                if (QKV) {
                    int wq = col / C;
                    int rem = col - wq * C;
                    int hh = rem >> 6, dd = rem & 63;
                    int bb2 = row >> 11, tt = row & 2047;
                    out[(((size_t)wq * (B*H) + bb2 * H + hh) * T + tt) * 64 + dd] = (OUT_T)v;
                } else {
                    out[(size_t)row * N + col] = (OUT_T)v;
                }
            }
        }
}

// ------- qk tile pass: one block per lower-triangle (qt,jt) tile --------------
// writes e = exp(q·k/8) (f16, causal-masked zeros on diagonal tile) to c
__global__ __launch_bounds__(256) void qk_tileA(const _Float16* __restrict__ qh,
        const _Float16* __restrict__ kh, half_t* __restrict__ c_h) {
    int p = blockIdx.x, bh = blockIdx.y;
    int qt = (int)((sqrtf(8.f * (float)p + 1.f) - 1.f) * 0.5f);
    while ((qt + 1) * (qt + 2) / 2 <= p) ++qt;
    while (qt * (qt + 1) / 2 > p) --qt;
    int jt = p - qt * (qt + 1) / 2;
    int tid = threadIdx.x, lane = tid & 63, wave = tid >> 6;
    int wr = wave >> 1, wc = wave & 1;
    int lrow = lane & 15, lseg = lane >> 4;
    int orow = (lane >> 4) * 4, ocol = lane & 15;
    __shared__ __align__(16) _Float16 Qs[64][72];
    __shared__ __align__(16) _Float16 Ks[64][72];
    const _Float16* qb = qh + ((size_t)bh * T + qt * 64) * 64;
    const _Float16* kb = kh + ((size_t)bh * T + jt * 64) * 64;
#pragma unroll
    for (int k = 0; k < 2; ++k) {
        int cc = k * 256 + tid;
        int r = cc >> 3, sg = cc & 7;
        *(f16x8*)&Qs[r][sg*8] = *(const f16x8*)&qb[r*64 + sg*8];
        *(f16x8*)&Ks[r][sg*8] = *(const f16x8*)&kb[r*64 + sg*8];
    }
    __syncthreads();
    f32x4 acc[2][2] = {};
    f16x8 af[2], bf[2];
#pragma unroll
    for (int i = 0; i < 2; ++i) af[i] = *(const f16x8*)&Qs[wr*32+i*16+lrow][lseg*8];
#pragma unroll
    for (int j = 0; j < 2; ++j) bf[j] = *(const f16x8*)&Ks[wc*32+j*16+lrow][lseg*8];
#pragma unroll
    for (int i = 0; i < 2; ++i)
#pragma unroll
        for (int j = 0; j < 2; ++j)
            acc[i][j] = __builtin_amdgcn_mfma_f32_16x16x32_f16(af[i], bf[j], acc[i][j], 0,0,0);
#pragma unroll
    for (int i = 0; i < 2; ++i) af[i] = *(const f16x8*)&Qs[wr*32+i*16+lrow][32+lseg*8];
#pragma unroll
    for (int j = 0; j < 2; ++j) bf[j] = *(const f16x8*)&Ks[wc*32+j*16+lrow][32+lseg*8];
#pragma unroll
    for (int i = 0; i < 2; ++i)
#pragma unroll
        for (int j = 0; j < 2; ++j)
            acc[i][j] = __builtin_amdgcn_mfma_f32_16x16x32_f16(af[i], bf[j], acc[i][j], 0,0,0);
    __syncthreads();                   // Ks reads done -> reuse as staging
    bool diag = (qt == jt);
#pragma unroll
    for (int i = 0; i < 2; ++i)
#pragma unroll
        for (int r = 0; r < 4; ++r) {
            int rl = wr*32 + i*16 + orow + r;
#pragma unroll
            for (int j = 0; j < 2; ++j) {
                int cl = wc*32 + j*16 + ocol;
                float s = acc[i][j][r] * 0.125f;
                float e = (diag && cl > rl) ? 0.f : __expf(s);
                Ks[rl][cl] = (_Float16)e;
            }
        }
    __syncthreads();
    half_t* cb = c_h + ((size_t)bh * T + qt * 64) * T + jt * 64;
#pragma unroll
    for (int k = 0; k < 2; ++k) {
        int cc = k * 256 + tid;
        int r = cc >> 3, sg = cc & 7;
        *(uint4*)&cb[(size_t)r * T + sg*8] = *(const uint4*)&Ks[r][sg*8];
    }
}

// ------- normalize rows of c in place + fold u0 (wave per row) ----------------
__global__ __launch_bounds__(256) void norm_u0(half_t* __restrict__ c_h,
        float* __restrict__ u) {
    int tid = threadIdx.x, lane = tid & 63, wid = tid >> 6;
    int row = blockIdx.x * 4 + wid;    // < 24576
    int bh = row >> 11, i = row & 2047;
    int qt = i >> 6, span = (qt + 1) * 64, nch = span >> 3;
    half_t* crow = c_h + ((size_t)bh * T + i) * T;
    uint4 raw[4];
    float z = 0.f;
#pragma unroll
    for (int k = 0; k < 4; ++k) {
        int ch = lane + k * 64;
        if (ch < nch) {
            uint4 rw = *(const uint4*)(crow + ch * 8);
            raw[k] = rw;
            const __half2* h2 = (const __half2*)&rw;
#pragma unroll
            for (int pp = 0; pp < 4; ++pp) {
                float2 cf = __half22float2(h2[pp]);
                z += cf.x + cf.y;
            }
        }
    }
    z = wave_allreduce_sum(z);
    float inv = 1.f / z;
    float S = 0.f;
#pragma unroll
    for (int k = 0; k < 4; ++k) {
        int ch = lane + k * 64;
        if (ch < nch) {
            uint4 rw = raw[k];
            const __half2* h2 = (const __half2*)&rw;
            union { __half2 h2o[4]; uint4 u4; } ou;
#pragma unroll
            for (int pp = 0; pp < 4; ++pp) {
                float2 cf = __half22float2(h2[pp]);
                float p0 = cf.x * inv, p1 = cf.y * inv;
                S += __expf(p0) + __expf(p1);
                ou.h2o[pp] = __floats2half2_rn(p0, p1);
            }
            *(uint4*)(crow + ch * 8) = ou.u4;
        }
    }
    S = wave_allreduce_sum(S);
    if (lane == 0) u[row] = -LOGT - logf(S + (float)(T - span));
}

// --------- scan: dst[bh*33+kt] = prefix/suffix tile sums of exp(src) ----------
template<int SUFFIX>
__global__ __launch_bounds__(256) void scan_exp_kernel(const float* __restrict__ src,
        float* __restrict__ dst) {
    int bh = blockIdx.x;
    int tid = threadIdx.x;
    __shared__ float part[256];
    __shared__ float ts[32];
    const float* s = src + (size_t)bh * T;
    float a = 0.f;
#pragma unroll
    for (int e = 0; e < 8; ++e) a += __expf(s[tid*8 + e]);
    part[tid] = a;
    __syncthreads();
    if (tid < 32) {
        float t0 = 0.f;
#pragma unroll
        for (int k = 0; k < 8; ++k) t0 += part[tid*8 + k];
        ts[tid] = t0;
    }
    __syncthreads();
    if (tid == 0) {
        if (SUFFIX) {
            float run = 0.f;
            dst[bh*33 + 32] = 0.f;
            for (int kt = 31; kt >= 0; --kt) { run += ts[kt]; dst[bh*33+kt] = run; }
        } else {
            float run = 0.f;
            for (int kt = 0; kt < 33; ++kt) { dst[bh*33+kt] = run; if (kt < 32) run += ts[kt]; }
        }
    }
}

// ---------------- col pass (causal): acc_j += sum_{r>=tile(j)} exp(c_rj+u_r) --
__global__ __launch_bounds__(256) void col_accum_causal(const half_t* __restrict__ c,
        const float* __restrict__ u, float* __restrict__ acc) {
    int jb = blockIdx.x * 256;
    int r0 = blockIdx.y * 128;
    int bh = blockIdx.z;
    if (r0 + 128 <= jb) return;
    int tid = threadIdx.x;
    int j = jb + tid;
    int rstart = r0, wtile = jb + (tid & ~63);
    if (wtile > rstart) rstart = wtile;
    int rend = r0 + 128;
    const half_t* cb = c + (size_t)bh * T * T;
    const float* ub = u + (size_t)bh * T;
    float a = 0.f;
    for (int r = rstart; r < rend; ++r)
        a += __expf(__half2float(cb[(size_t)r * T + j]) + ub[r]);
    if (rstart < rend) atomicAdd(&acc[(size_t)bh * T + j], a);
}

__global__ __launch_bounds__(256) void v_finalize2(const float* __restrict__ acc,
        const float* __restrict__ peu, float* __restrict__ v) {
    int idx = blockIdx.x * 256 + threadIdx.x;
    int bh = idx >> 11, j = idx & 2047;
    v[idx] = -LOGT - logf(acc[idx] + peu[bh*33 + (j >> 6)]);
}

// ---------------- row pass (causal): u_i = -logT - log(sum + Sev tail) --------
__global__ __launch_bounds__(256) void row_u_causal(const half_t* __restrict__ c,
        const float* __restrict__ v, const float* __restrict__ sev,
        float* __restrict__ u) {
    int row = blockIdx.x;
    int bh = row >> 11;
    int i = row & 2047;
    int qt = i >> 6;
    int nread = (qt + 1) << 6;
    int tid = threadIdx.x;
    const half_t* crow = c + (size_t)row * T;
    const float* vrow = v + (size_t)bh * T;
    float sum = 0.f;
    if (tid * 8 < nread) {
        uint4 raw = *(const uint4*)(crow + tid*8);
        const __half2* h2 = (const __half2*)&raw;
#pragma unroll
        for (int p = 0; p < 4; ++p) {
            float2 cf = __half22float2(h2[p]);
            sum += __expf(cf.x + vrow[tid*8 + p*2]);
            sum += __expf(cf.y + vrow[tid*8 + p*2 + 1]);
        }
    }
    float S = block_reduce_sum(sum);
    if (tid == 0) u[row] = -LOGT - logf(S + sev[bh*33 + qt + 1]);
}

// ---------------- Wsuf[kt][d] = sum_{tiles jt>=kt} sum_j exp(v_j) V[j][d] -----
__global__ __launch_bounds__(256) void wv_suffix_kernel(const _Float16* __restrict__ vh,
        const float* __restrict__ v, float* __restrict__ wsuf) {
    int bh = blockIdx.x;
    int tid = threadIdx.x;
    int d = tid & 63, g = tid >> 6;
    __shared__ float evs[2048];
    __shared__ float W[32][64];
    __shared__ float red[4][64];
    const float* vb = v + (size_t)bh * T;
#pragma unroll
    for (int k = 0; k < 8; ++k) evs[tid + k*256] = __expf(vb[tid + k*256]);
    __syncthreads();
    const _Float16* vbase = vh + (size_t)bh * T * 64;
    for (int jt = 0; jt < 32; ++jt) {
        float a = 0.f;
#pragma unroll
        for (int jj = 0; jj < 16; ++jj) {
            int j = jt*64 + g*16 + jj;
            a += evs[j] * (float)vbase[(size_t)j * 64 + d];
        }
        red[g][d] = a;
        __syncthreads();
        if (g == 0) W[jt][d] = red[0][d] + red[1][d] + red[2][d] + red[3][d];
        __syncthreads();
    }
    if (tid < 64) {
        float run = 0.f;
        wsuf[((size_t)bh*33 + 32)*64 + tid] = 0.f;
        for (int kt = 31; kt >= 0; --kt) {
            run += W[kt][tid];
            wsuf[((size_t)bh*33 + kt)*64 + tid] = run;
        }
    }
}

// ---------------- pv split-K: partial P@V chunks, f32 atomic accumulate -------
__global__ __launch_bounds__(256) void pv_split(const half_t* __restrict__ c_h,
        const float* __restrict__ u, const float* __restrict__ vv,
        const _Float16* __restrict__ vh, const float* __restrict__ wsuf,
        float* __restrict__ y32) {
    int qt = blockIdx.x, kc = blockIdx.y, bh = blockIdx.z;
    int j0 = kc * 8;
    if (j0 > qt) return;
    int jend = min(qt + 1, j0 + 8);
    int b = bh / H, h = bh - b * H;
    int tid = threadIdx.x, lane = tid & 63, wave = tid >> 6;
    int wr = wave >> 1, wc = wave & 1;
    int lrow = lane & 15, lseg = lane >> 4;
    int orow = (lane >> 4) * 4, ocol = lane & 15;
    __shared__ __align__(16) _Float16 Ps[64][72];
    __shared__ __align__(16) _Float16 Vt[64][72];
    __shared__ float us[64], vs[64], eus[64], wsf[64];
    if (tid < 64) {
        float uu = u[(size_t)bh*T + qt*64 + tid] + LOGT;
        us[tid] = uu;
        if (kc == 0) {
            eus[tid] = __expf(uu);
            wsf[tid] = wsuf[((size_t)bh*33 + qt + 1)*64 + tid];
        }
    }
    f32x4 acc[2][2] = {};
    const half_t* cb0 = c_h + ((size_t)bh*T + qt*64)*T;
    for (int jt = j0; jt < jend; ++jt) {
        __syncthreads();
        if (tid < 64) vs[tid] = vv[(size_t)bh*T + jt*64 + tid];
        __syncthreads();
        // stage P = exp(c + u + v + logT), f16
#pragma unroll
        for (int k = 0; k < 2; ++k) {
            int cc = k*256 + tid;
            int r = cc >> 3, sg = cc & 7;
            uint4 rw = *(const uint4*)&cb0[(size_t)r*T + jt*64 + sg*8];
            const __half2* h2 = (const __half2*)&rw;
            float ur = us[r];
            f16x8 p8;
#pragma unroll
            for (int pp = 0; pp < 4; ++pp) {
                float2 cf = __half22float2(h2[pp]);
                p8[pp*2]   = (_Float16)__expf(cf.x + ur + vs[sg*8 + pp*2]);
                p8[pp*2+1] = (_Float16)__expf(cf.y + ur + vs[sg*8 + pp*2 + 1]);
            }
            *(f16x8*)&Ps[r][sg*8] = p8;
        }
        // stage V^T: lane j = lane, d8 per (wave,k); conflict-free b16 writes
        {
            const _Float16* vb = vh + ((size_t)bh*T + jt*64)*64;
#pragma unroll
            for (int k = 0; k < 2; ++k) {
                int d8 = (wave*2 + k) * 8;
                f16x8 v8 = *(const f16x8*)&vb[(size_t)lane*64 + d8];
#pragma unroll
                for (int e = 0; e < 8; ++e) Vt[d8 + e][lane] = v8[e];
            }
        }
        __syncthreads();
        f16x8 af[2], bf[2];
#pragma unroll
        for (int i = 0; i < 2; ++i) af[i] = *(const f16x8*)&Ps[wr*32+i*16+lrow][lseg*8];
#pragma unroll
        for (int j = 0; j < 2; ++j) bf[j] = *(const f16x8*)&Vt[wc*32+j*16+lrow][lseg*8];
#pragma unroll
        for (int i = 0; i < 2; ++i)
#pragma unroll
            for (int j = 0; j < 2; ++j)
                acc[i][j] = __builtin_amdgcn_mfma_f32_16x16x32_f16(af[i], bf[j], acc[i][j], 0,0,0);
#pragma unroll
        for (int i = 0; i < 2; ++i) af[i] = *(const f16x8*)&Ps[wr*32+i*16+lrow][32+lseg*8];
#pragma unroll
        for (int j = 0; j < 2; ++j) bf[j] = *(const f16x8*)&Vt[wc*32+j*16+lrow][32+lseg*8];
#pragma unroll
        for (int i = 0; i < 2; ++i)
#pragma unroll
            for (int j = 0; j < 2; ++j)
                acc[i][j] = __builtin_amdgcn_mfma_f32_16x16x32_f16(af[i], bf[j], acc[i][j], 0,0,0);
    }
#pragma unroll
    for (int i = 0; i < 2; ++i)
#pragma unroll
        for (int j = 0; j < 2; ++j)
#pragma unroll
            for (int r = 0; r < 4; ++r) {
                int rl = wr*32 + i*16 + orow + r;
                int cl = wc*32 + j*16 + ocol;
                float val = acc[i][j][r];
                if (kc == 0) val += eus[rl] * wsf[cl];
                atomicAdd(&y32[((size_t)b*T + qt*64 + rl)*C + h*HD + cl], val);
            }
}

// -----------------------------------------------------------------------------
extern "C" void kernel_launch(void* const* d_in, const int* in_sizes, int n_in,
                              void* d_out, int out_size, void* d_ws, size_t ws_size,
                              hipStream_t stream) {
    (void)in_sizes; (void)n_in; (void)out_size;
    const float* x      = (const float*)d_in[0];
    const float* t      = (const float*)d_in[1];
    const float* ln1_w  = (const float*)d_in[2];
    const float* ln1_b  = (const float*)d_in[3];
    const float* attn_w = (const float*)d_in[4];
    const float* attn_b = (const float*)d_in[5];
    const float* proj_w = (const float*)d_in[6];
    const float* proj_b = (const float*)d_in[7];
    const float* ln2_w  = (const float*)d_in[8];
    const float* ln2_b  = (const float*)d_in[9];
    const float* fc_w   = (const float*)d_in[10];
    const float* fc_b   = (const float*)d_in[11];
    const float* fc2_w  = (const float*)d_in[12];
    const float* fc2_b  = (const float*)d_in[13];
    float* out = (float*)d_out;

    // ---- workspace layout (121,482,240 bytes) ----
    if (ws_size < 121482240ull) return;
    char* wsb = (char*)d_ws;
    half_t*    c_h  = (half_t*)wsb;                          // 100,663,296
    _Float16*  qkvh = (_Float16*)(wsb + 100663296ull);       // 9,437,184: q|k|v head-major
    float*     y32  = (float*)(wsb + 110100480ull);          // 6,291,456
    _Float16*  xh   = (_Float16*)(wsb + 116391936ull);       // 3,407,872
    _Float16*  wbuf = (_Float16*)(wsb + 119799808ull);       // 1,277,952
    float*     u    = (float*)(wsb + 121077760ull);          // BHT
    float*     vv   = u    + BHT;
    float*     cacc = vv   + BHT;
    float*     peu  = cacc + BHT;                            // 12*33 (+pad)
    float*     sev  = peu  + 1024;
    float*     wsuf = sev  + 1024;                           // 12*33*64
    // aliases:
    const _Float16* qh = qkvh;
    const _Float16* kh = qkvh + (size_t)(B*H) * T * 64;
    const _Float16* vh = qkvh + (size_t)2 * (B*H) * T * 64;
    _Float16* xn_h = xh;               // ln1 out -> qkv gemm in
    _Float16* hn_h = xh;               // ln2 out -> fc in (xh dead)
    float*    hb   = (float*)qkvh;     // proj out (qkvh dead after pv)
    _Float16* mb_h = (_Float16*)wsb;   // fc out (c dead after pv)

    const int M = B * T;   // 4096
    const int KP1 = 416;   // (C+1) padded to 32

    // ---- attention sub-block ----
    addtime_ln_f16<<<M, 256, 0, stream>>>(x, t, ln1_w, ln1_b, xn_h, KP1);
    convtrans_kernel<<<dim3(KP1/32, (3*C)/32), 256, 0, stream>>>(attn_w, wbuf, C+1, 3*C, KP1);
    mfma_gemm<0, 1, _Float16, _Float16><<<dim3(3*C/64, M/64), 256, 0, stream>>>(
        xn_h, wbuf, attn_b, qkvh, M, 3*C, KP1);
    qk_tileA<<<dim3(528, B*H), 256, 0, stream>>>(qh, kh, c_h);
    norm_u0<<<BHT/4, 256, 0, stream>>>(c_h, u);                             // u0

    // ---- sinkhorn iters: v1,u2,v3,u4,v5 (u0 folded above) ----
    scan_exp_kernel<0><<<B*H, 256, 0, stream>>>(u, peu);
    for (int it = 0; it < 3; ++it) {
        zerof_kernel<<<BHT/256, 256, 0, stream>>>(cacc);
        col_accum_causal<<<dim3(T/256, T/128, B*H), 256, 0, stream>>>(c_h, u, cacc);
        v_finalize2<<<BHT/256, 256, 0, stream>>>(cacc, peu, vv);
        if (it < 2) {
            scan_exp_kernel<1><<<B*H, 256, 0, stream>>>(vv, sev);
            row_u_causal<<<BHT, 256, 0, stream>>>(c_h, vv, sev, u);
            scan_exp_kernel<0><<<B*H, 256, 0, stream>>>(u, peu);
        }
    }
    wv_suffix_kernel<<<B*H, 256, 0, stream>>>(vh, vv, wsuf);
    zerof_kernel<<<(M*C)/256, 256, 0, stream>>>(y32);
    pv_split<<<dim3(T/64, 4, B*H), 256, 0, stream>>>(c_h, u, vv, vh, wsuf, y32);

    convtrans_kernel<<<dim3(C/32, C/32), 256, 0, stream>>>(proj_w, wbuf, C, C, C);
    mfma_gemm<0, 0, float, float><<<dim3(C/64, M/64), 256, 0, stream>>>(
        y32, wbuf, proj_b, hb, M, C, C);

    // ---- MLP sub-block ----
    addtime_ln_f16<<<M, 256, 0, stream>>>(hb, t, ln2_w, ln2_b, hn_h, KP1);
    convtrans_kernel<<<dim3(KP1/32, (4*C)/32), 256, 0, stream>>>(fc_w, wbuf, C+1, 4*C, KP1);
    mfma_gemm<1, 0, _Float16, _Float16><<<dim3(4*C/64, M/64), 256, 0, stream>>>(
        hn_h, wbuf, fc_b, mb_h, M, 4*C, KP1);
    convtrans_kernel<<<dim3((4*C)/32, C/32), 256, 0, stream>>>(fc2_w, wbuf, 4*C, C, 4*C);
    mfma_gemm<0, 0, _Float16, float><<<dim3(C/64, M/64), 256, 0, stream>>>(
        mb_h, wbuf, fc2_b, out, M, C, 4*C);
}

// Round 7
// 348.252 us; speedup vs baseline: 3.1775x; 1.2584x over previous
//
#include <hip/hip_runtime.h>
#include <hip/hip_fp16.h>
#include <math.h>

#define B 2
#define T 2048
#define C 384
#define H 6
#define HD 64
#define BHT (B*H*T)                    // 24576
#define LOGT 7.6246189861593985f       // log(2048)

typedef __half half_t;
typedef _Float16 f16x8 __attribute__((ext_vector_type(8)));
typedef float f32x4 __attribute__((ext_vector_type(4)));

// ---------------- reduction helpers ------------------------------------------
__device__ __forceinline__ float block_reduce_sum(float v) {
    __shared__ float sm[4];
    int lane = threadIdx.x & 63, wid = threadIdx.x >> 6;
#pragma unroll
    for (int o = 32; o > 0; o >>= 1) v += __shfl_down(v, o, 64);
    __syncthreads();
    if (lane == 0) sm[wid] = v;
    __syncthreads();
    return sm[0] + sm[1] + sm[2] + sm[3];
}

__device__ __forceinline__ float wave_allreduce_sum(float v) {
#pragma unroll
    for (int o = 1; o < 64; o <<= 1) v += __shfl_xor(v, o, 64);
    return v;
}

__global__ __launch_bounds__(256) void zerof_kernel(float* __restrict__ p) {
    p[(size_t)blockIdx.x * 256 + threadIdx.x] = 0.f;
}

// ---------------- add_time + layernorm -> f16 rows (stride KP, zero-padded) ---
__global__ __launch_bounds__(256) void addtime_ln_f16(
        const float* __restrict__ src, const float* __restrict__ tptr,
        const float* __restrict__ w, const float* __restrict__ bb,
        _Float16* __restrict__ dst, int KP) {
    const int n = C + 1;               // 385
    int row = blockIdx.x;              // over B*T
    const float* srow = src + (size_t)row * C;
    float tval = tptr[0];
    int i0 = threadIdx.x;
    int i1 = threadIdx.x + 256;
    float v0 = srow[i0];
    bool has1 = (i1 < n);
    float v1 = 0.f;
    if (has1) v1 = (i1 < C) ? srow[i1] : tval;
    float s  = block_reduce_sum(v0 + v1);
    float sq = block_reduce_sum(v0*v0 + v1*v1);
    float mean = s / n;
    float var  = sq / n - mean * mean;
    float rstd = rsqrtf(var + 1e-5f);
    _Float16* drow = dst + (size_t)row * KP;
    drow[i0] = (_Float16)((v0 - mean) * rstd * w[i0] + bb[i0]);
    if (has1) drow[i1] = (_Float16)((v1 - mean) * rstd * w[i1] + bb[i1]);
    else if (i1 < KP) drow[i1] = (_Float16)0.f;
}

// ------- weight convert+transpose: W (K×N fp32) -> Wt (N×KP f16, zero-pad) ----
__global__ __launch_bounds__(256) void convtrans_kernel(const float* __restrict__ W,
        _Float16* __restrict__ Wt, int K, int N, int KP) {
    __shared__ float tile[32][33];
    int k0 = blockIdx.x * 32, n0 = blockIdx.y * 32;
    int tx = threadIdx.x & 31, ty = threadIdx.x >> 5;
#pragma unroll
    for (int i = 0; i < 4; ++i) {
        int k = k0 + ty + i * 8, n = n0 + tx;
        tile[ty + i * 8][tx] = (k < K && n < N) ? W[(size_t)k * N + n] : 0.f;
    }
    __syncthreads();
#pragma unroll
    for (int i = 0; i < 4; ++i) {
        int n = n0 + ty + i * 8, k = k0 + tx;
        if (n < N && k < KP) Wt[(size_t)n * KP + k] = (_Float16)tile[tx][ty + i * 8];
    }
}

// ---------------- LDS A-stage loaders (f16 or f32 source) ---------------------
__device__ __forceinline__ f16x8 load8(const _Float16* p) { return *(const f16x8*)p; }
__device__ __forceinline__ f16x8 load8(const float* p) {
    float4 a = *(const float4*)p, b2 = *(const float4*)(p + 4);
    f16x8 r;
    r[0]=(_Float16)a.x; r[1]=(_Float16)a.y; r[2]=(_Float16)a.z; r[3]=(_Float16)a.w;
    r[4]=(_Float16)b2.x; r[5]=(_Float16)b2.y; r[6]=(_Float16)b2.z; r[7]=(_Float16)b2.w;
    return r;
}

// ---------------- f16 MFMA GEMM: out = A(M×KP) @ Wt(N×KP)^T + bias ------------
// ACT: 0 none, 1 exact gelu.  QKV: 1 => write f16 head-major q/k/v layout.
template<int ACT, int QKV, typename AT, typename OUT_T>
__global__ __launch_bounds__(256) void mfma_gemm(
        const AT* __restrict__ A, const _Float16* __restrict__ Wt,
        const float* __restrict__ bias, OUT_T* __restrict__ out,
        int M, int N, int KP) {
    __shared__ __align__(16) _Float16 As[64][40];
    __shared__ __align__(16) _Float16 Bs[64][40];
    int tid = threadIdx.x;
    int lane = tid & 63, wave = tid >> 6;
    int wr = wave >> 1, wc = wave & 1;
    int m0 = blockIdx.y * 64, n0 = blockIdx.x * 64;
    int arow = tid >> 2, seg = tid & 3;
    int lrow = lane & 15, lseg = lane >> 4;
    f32x4 acc[2][2] = {};
    for (int k0 = 0; k0 < KP; k0 += 32) {
        __syncthreads();
        *(f16x8*)&As[arow][seg * 8] = load8(&A[(size_t)(m0 + arow) * KP + k0 + seg * 8]);
        *(f16x8*)&Bs[arow][seg * 8] = *(const f16x8*)&Wt[(size_t)(n0 + arow) * KP + k0 + seg * 8];
        __syncthreads();
        f16x8 af[2], bf[2];
#pragma unroll
        for (int i = 0; i < 2; ++i) af[i] = *(const f16x8*)&As[wr*32 + i*16 + lrow][lseg*8];
#pragma unroll
        for (int j = 0; j < 2; ++j) bf[j] = *(const f16x8*)&Bs[wc*32 + j*16 + lrow][lseg*8];
#pragma unroll
        for (int i = 0; i < 2; ++i)
#pragma unroll
            for (int j = 0; j < 2; ++j)
                acc[i][j] = __builtin_amdgcn_mfma_f32_16x16x32_f16(af[i], bf[j], acc[i][j], 0, 0, 0);
    }
    int lcol = lane & 15, lr4 = (lane >> 4) * 4;
#pragma unroll
    for (int i = 0; i < 2; ++i)
#pragma unroll
        for (int j = 0; j < 2; ++j) {
            int col = n0 + wc * 32 + j * 16 + lcol;
            float bv = bias[col];
#pragma unroll
            for (int r = 0; r < 4; ++r) {
                int row = m0 + wr * 32 + i * 16 + lr4 + r;
                float v = acc[i][j][r] + bv;
                if (ACT == 1) v = 0.5f * v * (1.f + erff(v * 0.70710678118654752f));
                if (QKV) {
                    int wq = col / C;
                    int rem = col - wq * C;
                    int hh = rem >> 6, dd = rem & 63;
                    int bb2 = row >> 11, tt = row & 2047;
                    out[(((size_t)wq * (B*H) + bb2 * H + hh) * T + tt) * 64 + dd] = (OUT_T)v;
                } else {
                    out[(size_t)row * N + col] = (OUT_T)v;
                }
            }
        }
}

// ------- qk tile pass: one block per lower-triangle (qt,jt) tile --------------
// writes e = exp(q·k/8) (f16, causal-masked zeros on diagonal tile) to c
__global__ __launch_bounds__(256) void qk_tileA(const _Float16* __restrict__ qh,
        const _Float16* __restrict__ kh, half_t* __restrict__ c_h) {
    int p = blockIdx.x, bh = blockIdx.y;
    int qt = (int)((sqrtf(8.f * (float)p + 1.f) - 1.f) * 0.5f);
    while ((qt + 1) * (qt + 2) / 2 <= p) ++qt;
    while (qt * (qt + 1) / 2 > p) --qt;
    int jt = p - qt * (qt + 1) / 2;
    int tid = threadIdx.x, lane = tid & 63, wave = tid >> 6;
    int wr = wave >> 1, wc = wave & 1;
    int lrow = lane & 15, lseg = lane >> 4;
    int orow = (lane >> 4) * 4, ocol = lane & 15;
    __shared__ __align__(16) _Float16 Qs[64][72];
    __shared__ __align__(16) _Float16 Ks[64][72];
    const _Float16* qb = qh + ((size_t)bh * T + qt * 64) * 64;
    const _Float16* kb = kh + ((size_t)bh * T + jt * 64) * 64;
#pragma unroll
    for (int k = 0; k < 2; ++k) {
        int cc = k * 256 + tid;
        int r = cc >> 3, sg = cc & 7;
        *(f16x8*)&Qs[r][sg*8] = *(const f16x8*)&qb[r*64 + sg*8];
        *(f16x8*)&Ks[r][sg*8] = *(const f16x8*)&kb[r*64 + sg*8];
    }
    __syncthreads();
    f32x4 acc[2][2] = {};
    f16x8 af[2], bf[2];
#pragma unroll
    for (int i = 0; i < 2; ++i) af[i] = *(const f16x8*)&Qs[wr*32+i*16+lrow][lseg*8];
#pragma unroll
    for (int j = 0; j < 2; ++j) bf[j] = *(const f16x8*)&Ks[wc*32+j*16+lrow][lseg*8];
#pragma unroll
    for (int i = 0; i < 2; ++i)
#pragma unroll
        for (int j = 0; j < 2; ++j)
            acc[i][j] = __builtin_amdgcn_mfma_f32_16x16x32_f16(af[i], bf[j], acc[i][j], 0,0,0);
#pragma unroll
    for (int i = 0; i < 2; ++i) af[i] = *(const f16x8*)&Qs[wr*32+i*16+lrow][32+lseg*8];
#pragma unroll
    for (int j = 0; j < 2; ++j) bf[j] = *(const f16x8*)&Ks[wc*32+j*16+lrow][32+lseg*8];
#pragma unroll
    for (int i = 0; i < 2; ++i)
#pragma unroll
        for (int j = 0; j < 2; ++j)
            acc[i][j] = __builtin_amdgcn_mfma_f32_16x16x32_f16(af[i], bf[j], acc[i][j], 0,0,0);
    __syncthreads();                   // Ks reads done -> reuse as staging
    bool diag = (qt == jt);
#pragma unroll
    for (int i = 0; i < 2; ++i)
#pragma unroll
        for (int r = 0; r < 4; ++r) {
            int rl = wr*32 + i*16 + orow + r;
#pragma unroll
            for (int j = 0; j < 2; ++j) {
                int cl = wc*32 + j*16 + ocol;
                float s = acc[i][j][r] * 0.125f;
                float e = (diag && cl > rl) ? 0.f : __expf(s);
                Ks[rl][cl] = (_Float16)e;
            }
        }
    __syncthreads();
    half_t* cb = c_h + ((size_t)bh * T + qt * 64) * T + jt * 64;
#pragma unroll
    for (int k = 0; k < 2; ++k) {
        int cc = k * 256 + tid;
        int r = cc >> 3, sg = cc & 7;
        *(uint4*)&cb[(size_t)r * T + sg*8] = *(const uint4*)&Ks[r][sg*8];
    }
}

// ------- normalize rows in place, store q = exp(p), fold eu0 (wave/row) -------
// eu = exp(u) = 1/(T * (S + (T-span)))  [multiplicative sinkhorn scaling]
__global__ __launch_bounds__(256) void norm_q_u0(half_t* __restrict__ c_h,
        float* __restrict__ eu) {
    int tid = threadIdx.x, lane = tid & 63, wid = tid >> 6;
    int row = blockIdx.x * 4 + wid;    // < 24576
    int bh = row >> 11, i = row & 2047;
    int qt = i >> 6, span = (qt + 1) * 64, nch = span >> 3;
    half_t* crow = c_h + ((size_t)bh * T + i) * T;
    uint4 raw[4];
    float z = 0.f;
#pragma unroll
    for (int k = 0; k < 4; ++k) {
        int ch = lane + k * 64;
        if (ch < nch) {
            uint4 rw = *(const uint4*)(crow + ch * 8);
            raw[k] = rw;
            const __half2* h2 = (const __half2*)&rw;
#pragma unroll
            for (int pp = 0; pp < 4; ++pp) {
                float2 cf = __half22float2(h2[pp]);
                z += cf.x + cf.y;
            }
        }
    }
    z = wave_allreduce_sum(z);
    float inv = 1.f / z;
    float S = 0.f;
#pragma unroll
    for (int k = 0; k < 4; ++k) {
        int ch = lane + k * 64;
        if (ch < nch) {
            uint4 rw = raw[k];
            const __half2* h2 = (const __half2*)&rw;
            union { __half2 h2o[4]; uint4 u4; } ou;
#pragma unroll
            for (int pp = 0; pp < 4; ++pp) {
                float2 cf = __half22float2(h2[pp]);
                float q0 = __expf(cf.x * inv), q1 = __expf(cf.y * inv);
                S += q0 + q1;
                ou.h2o[pp] = __floats2half2_rn(q0, q1);
            }
            *(uint4*)(crow + ch * 8) = ou.u4;
        }
    }
    S = wave_allreduce_sum(S);
    if (lane == 0) eu[row] = 1.f / (2048.f * (S + (float)(T - span)));
}

// --------- scan: dst[bh*33+kt] = prefix/suffix tile sums of src (no exp) ------
template<int SUFFIX>
__global__ __launch_bounds__(256) void scan_sum_kernel(const float* __restrict__ src,
        float* __restrict__ dst) {
    int bh = blockIdx.x;
    int tid = threadIdx.x;
    __shared__ float part[256];
    __shared__ float ts[32];
    const float* s = src + (size_t)bh * T;
    float a = 0.f;
#pragma unroll
    for (int e = 0; e < 8; ++e) a += s[tid*8 + e];
    part[tid] = a;
    __syncthreads();
    if (tid < 32) {
        float t0 = 0.f;
#pragma unroll
        for (int k = 0; k < 8; ++k) t0 += part[tid*8 + k];
        ts[tid] = t0;
    }
    __syncthreads();
    if (tid == 0) {
        if (SUFFIX) {
            float run = 0.f;
            dst[bh*33 + 32] = 0.f;
            for (int kt = 31; kt >= 0; --kt) { run += ts[kt]; dst[bh*33+kt] = run; }
        } else {
            float run = 0.f;
            for (int kt = 0; kt < 33; ++kt) { dst[bh*33+kt] = run; if (kt < 32) run += ts[kt]; }
        }
    }
}

// ---------------- col pass (causal, multiplicative): acc_j += q_rj * eu_r -----
__global__ __launch_bounds__(256) void col_accum_mult(const half_t* __restrict__ c,
        const float* __restrict__ eu, float* __restrict__ acc) {
    int jb = blockIdx.x * 256;
    int r0 = blockIdx.y * 128;
    int bh = blockIdx.z;
    if (r0 + 128 <= jb) return;
    int tid = threadIdx.x;
    int j = jb + tid;
    int rstart = r0, wtile = jb + (tid & ~63);
    if (wtile > rstart) rstart = wtile;
    int rend = r0 + 128;
    const half_t* cb = c + (size_t)bh * T * T + j;
    const float* eub = eu + (size_t)bh * T;
    float a = 0.f;
#pragma unroll 8
    for (int r = rstart; r < rend; ++r)
        a = fmaf(__half2float(cb[(size_t)r * T]), eub[r], a);
    if (rstart < rend) atomicAdd(&acc[(size_t)bh * T + j], a);
}

// ev = 1 / (T * (acc + prefix_eu))
__global__ __launch_bounds__(256) void v_finalize_mult(const float* __restrict__ acc,
        const float* __restrict__ peu, float* __restrict__ ev) {
    int idx = blockIdx.x * 256 + threadIdx.x;
    int bh = idx >> 11, j = idx & 2047;
    ev[idx] = 1.f / (2048.f * (acc[idx] + peu[bh*33 + (j >> 6)]));
}

// ---- row pass (causal, multiplicative): eu_i = 1/(T*(sum q*ev + sev tail)) ---
__global__ __launch_bounds__(256) void row_eu_mult(const half_t* __restrict__ c,
        const float* __restrict__ ev, const float* __restrict__ sev,
        float* __restrict__ eu) {
    int tid = threadIdx.x, lane = tid & 63, wid = tid >> 6;
    int row = blockIdx.x * 4 + wid;
    int bh = row >> 11, i = row & 2047;
    int qt = i >> 6, nch = ((qt + 1) << 6) >> 3;
    const half_t* crow = c + ((size_t)bh * T + i) * T;
    const float* evb = ev + (size_t)bh * T;
    float s = 0.f;
#pragma unroll
    for (int k = 0; k < 4; ++k) {
        int ch = lane + k * 64;
        if (ch < nch) {
            uint4 rw = *(const uint4*)(crow + ch * 8);
            const __half2* h2 = (const __half2*)&rw;
            float4 e0 = *(const float4*)(evb + ch * 8);
            float4 e1 = *(const float4*)(evb + ch * 8 + 4);
            float2 c0 = __half22float2(h2[0]), c1 = __half22float2(h2[1]);
            float2 c2 = __half22float2(h2[2]), c3 = __half22float2(h2[3]);
            s = fmaf(c0.x, e0.x, s); s = fmaf(c0.y, e0.y, s);
            s = fmaf(c1.x, e0.z, s); s = fmaf(c1.y, e0.w, s);
            s = fmaf(c2.x, e1.x, s); s = fmaf(c2.y, e1.y, s);
            s = fmaf(c3.x, e1.z, s); s = fmaf(c3.y, e1.w, s);
        }
    }
    s = wave_allreduce_sum(s);
    if (lane == 0) eu[row] = 1.f / (2048.f * (s + sev[bh*33 + qt + 1]));
}

// ---------------- Wsuf[kt][d] = sum_{tiles jt>=kt} sum_j ev_j V[j][d] ---------
__global__ __launch_bounds__(256) void wv_suffix_kernel(const _Float16* __restrict__ vh,
        const float* __restrict__ ev, float* __restrict__ wsuf) {
    int bh = blockIdx.x;
    int tid = threadIdx.x;
    int d = tid & 63, g = tid >> 6;
    __shared__ float evs[2048];
    __shared__ float W[32][64];
    __shared__ float red[4][64];
    const float* vb = ev + (size_t)bh * T;
#pragma unroll
    for (int k = 0; k < 8; ++k) evs[tid + k*256] = vb[tid + k*256];
    __syncthreads();
    const _Float16* vbase = vh + (size_t)bh * T * 64;
    for (int jt = 0; jt < 32; ++jt) {
        float a = 0.f;
#pragma unroll
        for (int jj = 0; jj < 16; ++jj) {
            int j = jt*64 + g*16 + jj;
            a += evs[j] * (float)vbase[(size_t)j * 64 + d];
        }
        red[g][d] = a;
        __syncthreads();
        if (g == 0) W[jt][d] = red[0][d] + red[1][d] + red[2][d] + red[3][d];
        __syncthreads();
    }
    if (tid < 64) {
        float run = 0.f;
        wsuf[((size_t)bh*33 + 32)*64 + tid] = 0.f;
        for (int kt = 31; kt >= 0; --kt) {
            run += W[kt][tid];
            wsuf[((size_t)bh*33 + kt)*64 + tid] = run;
        }
    }
}

// ---------------- pv split-K: P = q * (eu*T) * ev, MFMA, f32 atomic accum -----
__global__ __launch_bounds__(256) void pv_split(const half_t* __restrict__ c_h,
        const float* __restrict__ eu, const float* __restrict__ ev,
        const _Float16* __restrict__ vh, const float* __restrict__ wsuf,
        float* __restrict__ y32) {
    int qt = blockIdx.x, kc = blockIdx.y, bh = blockIdx.z;
    int j0 = kc * 8;
    if (j0 > qt) return;
    int jend = min(qt + 1, j0 + 8);
    int b = bh / H, h = bh - b * H;
    int tid = threadIdx.x, lane = tid & 63, wave = tid >> 6;
    int wr = wave >> 1, wc = wave & 1;
    int lrow = lane & 15, lseg = lane >> 4;
    int orow = (lane >> 4) * 4, ocol = lane & 15;
    __shared__ __align__(16) _Float16 Ps[64][72];
    __shared__ __align__(16) _Float16 Vt[64][72];
    __shared__ float facs[64], vs[64], wsf[64];
    if (tid < 64) {
        facs[tid] = eu[(size_t)bh*T + qt*64 + tid] * 2048.f;
        if (kc == 0) wsf[tid] = wsuf[((size_t)bh*33 + qt + 1)*64 + tid];
    }
    f32x4 acc[2][2] = {};
    const half_t* cb0 = c_h + ((size_t)bh*T + qt*64)*T;
    for (int jt = j0; jt < jend; ++jt) {
        __syncthreads();
        if (tid < 64) vs[tid] = ev[(size_t)bh*T + jt*64 + tid];
        __syncthreads();
        // stage P = q * fac_r * ev_j, f16
#pragma unroll
        for (int k = 0; k < 2; ++k) {
            int cc = k*256 + tid;
            int r = cc >> 3, sg = cc & 7;
            uint4 rw = *(const uint4*)&cb0[(size_t)r*T + jt*64 + sg*8];
            const __half2* h2 = (const __half2*)&rw;
            float fr = facs[r];
            f16x8 p8;
#pragma unroll
            for (int pp = 0; pp < 4; ++pp) {
                float2 cf = __half22float2(h2[pp]);
                p8[pp*2]   = (_Float16)(cf.x * fr * vs[sg*8 + pp*2]);
                p8[pp*2+1] = (_Float16)(cf.y * fr * vs[sg*8 + pp*2 + 1]);
            }
            *(f16x8*)&Ps[r][sg*8] = p8;
        }
        // stage V^T: conflict-free b16 writes
        {
            const _Float16* vb = vh + ((size_t)bh*T + jt*64)*64;
#pragma unroll
            for (int k = 0; k < 2; ++k) {
                int d8 = (wave*2 + k) * 8;
                f16x8 v8 = *(const f16x8*)&vb[(size_t)lane*64 + d8];
#pragma unroll
                for (int e = 0; e < 8; ++e) Vt[d8 + e][lane] = v8[e];
            }
        }
        __syncthreads();
        f16x8 af[2], bf[2];
#pragma unroll
        for (int i = 0; i < 2; ++i) af[i] = *(const f16x8*)&Ps[wr*32+i*16+lrow][lseg*8];
#pragma unroll
        for (int j = 0; j < 2; ++j) bf[j] = *(const f16x8*)&Vt[wc*32+j*16+lrow][lseg*8];
#pragma unroll
        for (int i = 0; i < 2; ++i)
#pragma unroll
            for (int j = 0; j < 2; ++j)
                acc[i][j] = __builtin_amdgcn_mfma_f32_16x16x32_f16(af[i], bf[j], acc[i][j], 0,0,0);
#pragma unroll
        for (int i = 0; i < 2; ++i) af[i] = *(const f16x8*)&Ps[wr*32+i*16+lrow][32+lseg*8];
#pragma unroll
        for (int j = 0; j < 2; ++j) bf[j] = *(const f16x8*)&Vt[wc*32+j*16+lrow][32+lseg*8];
#pragma unroll
        for (int i = 0; i < 2; ++i)
#pragma unroll
            for (int j = 0; j < 2; ++j)
                acc[i][j] = __builtin_amdgcn_mfma_f32_16x16x32_f16(af[i], bf[j], acc[i][j], 0,0,0);
    }
#pragma unroll
    for (int i = 0; i < 2; ++i)
#pragma unroll
        for (int j = 0; j < 2; ++j)
#pragma unroll
            for (int r = 0; r < 4; ++r) {
                int rl = wr*32 + i*16 + orow + r;
                int cl = wc*32 + j*16 + ocol;
                float val = acc[i][j][r];
                if (kc == 0) val += facs[rl] * wsf[cl];
                atomicAdd(&y32[((size_t)b*T + qt*64 + rl)*C + h*HD + cl], val);
            }
}

// -----------------------------------------------------------------------------
extern "C" void kernel_launch(void* const* d_in, const int* in_sizes, int n_in,
                              void* d_out, int out_size, void* d_ws, size_t ws_size,
                              hipStream_t stream) {
    (void)in_sizes; (void)n_in; (void)out_size;
    const float* x      = (const float*)d_in[0];
    const float* t      = (const float*)d_in[1];
    const float* ln1_w  = (const float*)d_in[2];
    const float* ln1_b  = (const float*)d_in[3];
    const float* attn_w = (const float*)d_in[4];
    const float* attn_b = (const float*)d_in[5];
    const float* proj_w = (const float*)d_in[6];
    const float* proj_b = (const float*)d_in[7];
    const float* ln2_w  = (const float*)d_in[8];
    const float* ln2_b  = (const float*)d_in[9];
    const float* fc_w   = (const float*)d_in[10];
    const float* fc_b   = (const float*)d_in[11];
    const float* fc2_w  = (const float*)d_in[12];
    const float* fc2_b  = (const float*)d_in[13];
    float* out = (float*)d_out;

    // ---- workspace layout (121,482,240 bytes) ----
    if (ws_size < 121482240ull) return;
    char* wsb = (char*)d_ws;
    half_t*    c_h  = (half_t*)wsb;                          // 100,663,296
    _Float16*  qkvh = (_Float16*)(wsb + 100663296ull);       // 9,437,184: q|k|v head-major
    float*     y32  = (float*)(wsb + 110100480ull);          // 6,291,456
    _Float16*  xh   = (_Float16*)(wsb + 116391936ull);       // 3,407,872
    _Float16*  wbuf = (_Float16*)(wsb + 119799808ull);       // 1,277,952
    float*     eu   = (float*)(wsb + 121077760ull);          // BHT
    float*     ev   = eu   + BHT;
    float*     cacc = ev   + BHT;
    float*     peu  = cacc + BHT;                            // 12*33 (+pad)
    float*     sev  = peu  + 1024;
    float*     wsuf = sev  + 1024;                           // 12*33*64
    // aliases:
    const _Float16* qh = qkvh;
    const _Float16* kh = qkvh + (size_t)(B*H) * T * 64;
    const _Float16* vh = qkvh + (size_t)2 * (B*H) * T * 64;
    _Float16* xn_h = xh;               // ln1 out -> qkv gemm in
    _Float16* hn_h = xh;               // ln2 out -> fc in (xh dead)
    float*    hb   = (float*)qkvh;     // proj out (qkvh dead after pv)
    _Float16* mb_h = (_Float16*)wsb;   // fc out (c dead after pv)

    const int M = B * T;   // 4096
    const int KP1 = 416;   // (C+1) padded to 32

    // ---- attention sub-block ----
    addtime_ln_f16<<<M, 256, 0, stream>>>(x, t, ln1_w, ln1_b, xn_h, KP1);
    convtrans_kernel<<<dim3(KP1/32, (3*C)/32), 256, 0, stream>>>(attn_w, wbuf, C+1, 3*C, KP1);
    mfma_gemm<0, 1, _Float16, _Float16><<<dim3(3*C/64, M/64), 256, 0, stream>>>(
        xn_h, wbuf, attn_b, qkvh, M, 3*C, KP1);
    qk_tileA<<<dim3(528, B*H), 256, 0, stream>>>(qh, kh, c_h);
    norm_q_u0<<<BHT/4, 256, 0, stream>>>(c_h, eu);                          // q + eu0

    // ---- multiplicative sinkhorn iters: v1,u2,v3,u4,v5 (u0 folded above) ----
    scan_sum_kernel<0><<<B*H, 256, 0, stream>>>(eu, peu);
    for (int it = 0; it < 3; ++it) {
        zerof_kernel<<<BHT/256, 256, 0, stream>>>(cacc);
        col_accum_mult<<<dim3(T/256, T/128, B*H), 256, 0, stream>>>(c_h, eu, cacc);
        v_finalize_mult<<<BHT/256, 256, 0, stream>>>(cacc, peu, ev);
        if (it < 2) {
            scan_sum_kernel<1><<<B*H, 256, 0, stream>>>(ev, sev);
            row_eu_mult<<<BHT/4, 256, 0, stream>>>(c_h, ev, sev, eu);
            scan_sum_kernel<0><<<B*H, 256, 0, stream>>>(eu, peu);
        }
    }
    wv_suffix_kernel<<<B*H, 256, 0, stream>>>(vh, ev, wsuf);
    zerof_kernel<<<(M*C)/256, 256, 0, stream>>>(y32);
    pv_split<<<dim3(T/64, 4, B*H), 256, 0, stream>>>(c_h, eu, ev, vh, wsuf, y32);

    convtrans_kernel<<<dim3(C/32, C/32), 256, 0, stream>>>(proj_w, wbuf, C, C, C);
    mfma_gemm<0, 0, float, float><<<dim3(C/64, M/64), 256, 0, stream>>>(
        y32, wbuf, proj_b, hb, M, C, C);

    // ---- MLP sub-block ----
    addtime_ln_f16<<<M, 256, 0, stream>>>(hb, t, ln2_w, ln2_b, hn_h, KP1);
    convtrans_kernel<<<dim3(KP1/32, (4*C)/32), 256, 0, stream>>>(fc_w, wbuf, C+1, 4*C, KP1);
    mfma_gemm<1, 0, _Float16, _Float16><<<dim3(4*C/64, M/64), 256, 0, stream>>>(
        hn_h, wbuf, fc_b, mb_h, M, 4*C, KP1);
    convtrans_kernel<<<dim3((4*C)/32, C/32), 256, 0, stream>>>(fc2_w, wbuf, 4*C, C, 4*C);
    mfma_gemm<0, 0, _Float16, float><<<dim3(C/64, M/64), 256, 0, stream>>>(
        mb_h, wbuf, fc2_b, out, M, C, 4*C);
}

// Round 8
// 321.605 us; speedup vs baseline: 3.4408x; 1.0829x over previous
//
#include <hip/hip_runtime.h>
#include <hip/hip_fp16.h>
#include <math.h>

#define B 2
#define T 2048
#define C 384
#define H 6
#define HD 64
#define BHT (B*H*T)                    // 24576
#define LOGT 7.6246189861593985f       // log(2048)

typedef __half half_t;
typedef _Float16 f16x8 __attribute__((ext_vector_type(8)));
typedef float f32x4 __attribute__((ext_vector_type(4)));

// ---------------- reduction helpers ------------------------------------------
__device__ __forceinline__ float block_reduce_sum(float v) {
    __shared__ float sm[4];
    int lane = threadIdx.x & 63, wid = threadIdx.x >> 6;
#pragma unroll
    for (int o = 32; o > 0; o >>= 1) v += __shfl_down(v, o, 64);
    __syncthreads();
    if (lane == 0) sm[wid] = v;
    __syncthreads();
    return sm[0] + sm[1] + sm[2] + sm[3];
}

__device__ __forceinline__ float wave_allreduce_sum(float v) {
#pragma unroll
    for (int o = 1; o < 64; o <<= 1) v += __shfl_xor(v, o, 64);
    return v;
}

__global__ __launch_bounds__(256) void zerof_kernel(float* __restrict__ p) {
    p[(size_t)blockIdx.x * 256 + threadIdx.x] = 0.f;
}

// ---------------- add_time + layernorm -> f16 rows (stride KP, zero-padded) ---
__global__ __launch_bounds__(256) void addtime_ln_f16(
        const float* __restrict__ src, const float* __restrict__ tptr,
        const float* __restrict__ w, const float* __restrict__ bb,
        _Float16* __restrict__ dst, int KP) {
    const int n = C + 1;               // 385
    int row = blockIdx.x;              // over B*T
    const float* srow = src + (size_t)row * C;
    float tval = tptr[0];
    int i0 = threadIdx.x;
    int i1 = threadIdx.x + 256;
    float v0 = srow[i0];
    bool has1 = (i1 < n);
    float v1 = 0.f;
    if (has1) v1 = (i1 < C) ? srow[i1] : tval;
    float s  = block_reduce_sum(v0 + v1);
    float sq = block_reduce_sum(v0*v0 + v1*v1);
    float mean = s / n;
    float var  = sq / n - mean * mean;
    float rstd = rsqrtf(var + 1e-5f);
    _Float16* drow = dst + (size_t)row * KP;
    drow[i0] = (_Float16)((v0 - mean) * rstd * w[i0] + bb[i0]);
    if (has1) drow[i1] = (_Float16)((v1 - mean) * rstd * w[i1] + bb[i1]);
    else if (i1 < KP) drow[i1] = (_Float16)0.f;
}

// ------- weight convert+transpose: W (K×N fp32) -> Wt (N×KP f16, zero-pad) ----
__global__ __launch_bounds__(256) void convtrans_kernel(const float* __restrict__ W,
        _Float16* __restrict__ Wt, int K, int N, int KP) {
    __shared__ float tile[32][33];
    int k0 = blockIdx.x * 32, n0 = blockIdx.y * 32;
    int tx = threadIdx.x & 31, ty = threadIdx.x >> 5;
#pragma unroll
    for (int i = 0; i < 4; ++i) {
        int k = k0 + ty + i * 8, n = n0 + tx;
        tile[ty + i * 8][tx] = (k < K && n < N) ? W[(size_t)k * N + n] : 0.f;
    }
    __syncthreads();
#pragma unroll
    for (int i = 0; i < 4; ++i) {
        int n = n0 + ty + i * 8, k = k0 + tx;
        if (n < N && k < KP) Wt[(size_t)n * KP + k] = (_Float16)tile[tx][ty + i * 8];
    }
}

// ---------------- LDS A-stage loaders (f16 or f32 source) ---------------------
__device__ __forceinline__ f16x8 load8(const _Float16* p) { return *(const f16x8*)p; }
__device__ __forceinline__ f16x8 load8(const float* p) {
    float4 a = *(const float4*)p, b2 = *(const float4*)(p + 4);
    f16x8 r;
    r[0]=(_Float16)a.x; r[1]=(_Float16)a.y; r[2]=(_Float16)a.z; r[3]=(_Float16)a.w;
    r[4]=(_Float16)b2.x; r[5]=(_Float16)b2.y; r[6]=(_Float16)b2.z; r[7]=(_Float16)b2.w;
    return r;
}

// ---------------- f16 MFMA GEMM: out = A(M×KP) @ Wt(N×KP)^T + bias ------------
// ACT: 0 none, 1 exact gelu.  QKV: 1 => write f16 head-major q/k/v layout.
template<int ACT, int QKV, typename AT, typename OUT_T>
__global__ __launch_bounds__(256) void mfma_gemm(
        const AT* __restrict__ A, const _Float16* __restrict__ Wt,
        const float* __restrict__ bias, OUT_T* __restrict__ out,
        int M, int N, int KP) {
    __shared__ __align__(16) _Float16 As[64][40];
    __shared__ __align__(16) _Float16 Bs[64][40];
    int tid = threadIdx.x;
    int lane = tid & 63, wave = tid >> 6;
    int wr = wave >> 1, wc = wave & 1;
    int m0 = blockIdx.y * 64, n0 = blockIdx.x * 64;
    int arow = tid >> 2, seg = tid & 3;
    int lrow = lane & 15, lseg = lane >> 4;
    f32x4 acc[2][2] = {};
    for (int k0 = 0; k0 < KP; k0 += 32) {
        __syncthreads();
        *(f16x8*)&As[arow][seg * 8] = load8(&A[(size_t)(m0 + arow) * KP + k0 + seg * 8]);
        *(f16x8*)&Bs[arow][seg * 8] = *(const f16x8*)&Wt[(size_t)(n0 + arow) * KP + k0 + seg * 8];
        __syncthreads();
        f16x8 af[2], bf[2];
#pragma unroll
        for (int i = 0; i < 2; ++i) af[i] = *(const f16x8*)&As[wr*32 + i*16 + lrow][lseg*8];
#pragma unroll
        for (int j = 0; j < 2; ++j) bf[j] = *(const f16x8*)&Bs[wc*32 + j*16 + lrow][lseg*8];
#pragma unroll
        for (int i = 0; i < 2; ++i)
#pragma unroll
            for (int j = 0; j < 2; ++j)
                acc[i][j] = __builtin_amdgcn_mfma_f32_16x16x32_f16(af[i], bf[j], acc[i][j], 0, 0, 0);
    }
    int lcol = lane & 15, lr4 = (lane >> 4) * 4;
#pragma unroll
    for (int i = 0; i < 2; ++i)
#pragma unroll
        for (int j = 0; j < 2; ++j) {
            int col = n0 + wc * 32 + j * 16 + lcol;
            float bv = bias[col];
#pragma unroll
            for (int r = 0; r < 4; ++r) {
                int row = m0 + wr * 32 + i * 16 + lr4 + r;
                float v = acc[i][j][r] + bv;
                if (ACT == 1) v = 0.5f * v * (1.f + erff(v * 0.70710678118654752f));
                if (QKV) {
                    int wq = col / C;
                    int rem = col - wq * C;
                    int hh = rem >> 6, dd = rem & 63;
                    int bb2 = row >> 11, tt = row & 2047;
                    out[(((size_t)wq * (B*H) + bb2 * H + hh) * T + tt) * 64 + dd] = (OUT_T)v;
                } else {
                    out[(size_t)row * N + col] = (OUT_T)v;
                }
            }
        }
}

// ------- qk tile pass: one block per lower-triangle (qt,jt) tile --------------
// writes e = exp(q·k/8) (f16, causal-masked zeros on diagonal tile) to c
__global__ __launch_bounds__(256) void qk_tileA(const _Float16* __restrict__ qh,
        const _Float16* __restrict__ kh, half_t* __restrict__ c_h) {
    int p = blockIdx.x, bh = blockIdx.y;
    int qt = (int)((sqrtf(8.f * (float)p + 1.f) - 1.f) * 0.5f);
    while ((qt + 1) * (qt + 2) / 2 <= p) ++qt;
    while (qt * (qt + 1) / 2 > p) --qt;
    int jt = p - qt * (qt + 1) / 2;
    int tid = threadIdx.x, lane = tid & 63, wave = tid >> 6;
    int wr = wave >> 1, wc = wave & 1;
    int lrow = lane & 15, lseg = lane >> 4;
    int orow = (lane >> 4) * 4, ocol = lane & 15;
    __shared__ __align__(16) _Float16 Qs[64][72];
    __shared__ __align__(16) _Float16 Ks[64][72];
    const _Float16* qb = qh + ((size_t)bh * T + qt * 64) * 64;
    const _Float16* kb = kh + ((size_t)bh * T + jt * 64) * 64;
#pragma unroll
    for (int k = 0; k < 2; ++k) {
        int cc = k * 256 + tid;
        int r = cc >> 3, sg = cc & 7;
        *(f16x8*)&Qs[r][sg*8] = *(const f16x8*)&qb[r*64 + sg*8];
        *(f16x8*)&Ks[r][sg*8] = *(const f16x8*)&kb[r*64 + sg*8];
    }
    __syncthreads();
    f32x4 acc[2][2] = {};
    f16x8 af[2], bf[2];
#pragma unroll
    for (int i = 0; i < 2; ++i) af[i] = *(const f16x8*)&Qs[wr*32+i*16+lrow][lseg*8];
#pragma unroll
    for (int j = 0; j < 2; ++j) bf[j] = *(const f16x8*)&Ks[wc*32+j*16+lrow][lseg*8];
#pragma unroll
    for (int i = 0; i < 2; ++i)
#pragma unroll
        for (int j = 0; j < 2; ++j)
            acc[i][j] = __builtin_amdgcn_mfma_f32_16x16x32_f16(af[i], bf[j], acc[i][j], 0,0,0);
#pragma unroll
    for (int i = 0; i < 2; ++i) af[i] = *(const f16x8*)&Qs[wr*32+i*16+lrow][32+lseg*8];
#pragma unroll
    for (int j = 0; j < 2; ++j) bf[j] = *(const f16x8*)&Ks[wc*32+j*16+lrow][32+lseg*8];
#pragma unroll
    for (int i = 0; i < 2; ++i)
#pragma unroll
        for (int j = 0; j < 2; ++j)
            acc[i][j] = __builtin_amdgcn_mfma_f32_16x16x32_f16(af[i], bf[j], acc[i][j], 0,0,0);
    __syncthreads();                   // Ks reads done -> reuse as staging
    bool diag = (qt == jt);
#pragma unroll
    for (int i = 0; i < 2; ++i)
#pragma unroll
        for (int r = 0; r < 4; ++r) {
            int rl = wr*32 + i*16 + orow + r;
#pragma unroll
            for (int j = 0; j < 2; ++j) {
                int cl = wc*32 + j*16 + ocol;
                float s = acc[i][j][r] * 0.125f;
                float e = (diag && cl > rl) ? 0.f : __expf(s);
                Ks[rl][cl] = (_Float16)e;
            }
        }
    __syncthreads();
    half_t* cb = c_h + ((size_t)bh * T + qt * 64) * T + jt * 64;
#pragma unroll
    for (int k = 0; k < 2; ++k) {
        int cc = k * 256 + tid;
        int r = cc >> 3, sg = cc & 7;
        *(uint4*)&cb[(size_t)r * T + sg*8] = *(const uint4*)&Ks[r][sg*8];
    }
}

// ---- FUSED: normalize rows (q=exp(p)), eu0, and col-accumulate q^T·eu0 -------
// grid (64, B*H): block = half a row-tile (32 rows), 4 waves × 8 rows.
__global__ __launch_bounds__(256) void norm_q_col(half_t* __restrict__ c_h,
        float* __restrict__ eu, float* __restrict__ cacc) {
    int qt = blockIdx.x >> 1, half = blockIdx.x & 1, bh = blockIdx.y;
    int tid = threadIdx.x, lane = tid & 63, w = tid >> 6;
    int span = (qt + 1) * 64, nch = span >> 3;
    __shared__ float colacc[4][2048];
    float acc32[32];
#pragma unroll
    for (int k = 0; k < 32; ++k) acc32[k] = 0.f;
    half_t* cb = c_h + ((size_t)bh * T + qt * 64 + half * 32) * T;
    for (int rr = 0; rr < 8; ++rr) {
        int i = w * 8 + rr;            // row within half-tile
        half_t* crow = cb + (size_t)i * T;
        uint4 raw[4];
        float z = 0.f;
#pragma unroll
        for (int k = 0; k < 4; ++k) {
            int ch = lane + (k << 6);
            if (ch < nch) {
                uint4 rw = *(const uint4*)(crow + ch * 8);
                raw[k] = rw;
                const __half2* h2 = (const __half2*)&rw;
#pragma unroll
                for (int pp = 0; pp < 4; ++pp) {
                    float2 cf = __half22float2(h2[pp]);
                    z += cf.x + cf.y;
                }
            }
        }
        z = wave_allreduce_sum(z);
        float inv = 1.f / z;
        float qv[32];
        float S = 0.f;
#pragma unroll
        for (int k = 0; k < 4; ++k) {
            int ch = lane + (k << 6);
            if (ch < nch) {
                const __half2* h2 = (const __half2*)&raw[k];
                union { __half2 h[4]; uint4 u; } ou;
#pragma unroll
                for (int pp = 0; pp < 4; ++pp) {
                    float2 cf = __half22float2(h2[pp]);
                    float q0 = __expf(cf.x * inv), q1 = __expf(cf.y * inv);
                    S += q0 + q1;
                    qv[k*8+pp*2] = q0; qv[k*8+pp*2+1] = q1;
                    ou.h[pp] = __floats2half2_rn(q0, q1);
                }
                *(uint4*)(crow + ch * 8) = ou.u;
            }
        }
        S = wave_allreduce_sum(S);
        float eui = 1.f / (2048.f * (S + (float)(T - span)));
        if (lane == 0) eu[(size_t)bh * T + qt * 64 + half * 32 + i] = eui;
#pragma unroll
        for (int k = 0; k < 4; ++k) {
            int ch = lane + (k << 6);
            if (ch < nch)
#pragma unroll
                for (int e = 0; e < 8; ++e)
                    acc32[k*8+e] = fmaf(qv[k*8+e], eui, acc32[k*8+e]);
        }
    }
#pragma unroll
    for (int k = 0; k < 4; ++k) {
        int ch = lane + (k << 6);
        if (ch < nch)
#pragma unroll
            for (int e = 0; e < 8; ++e)
                colacc[w][ch*8+e] = acc32[k*8+e];
    }
    __syncthreads();
    for (int j = tid; j < span; j += 256)
        atomicAdd(&cacc[(size_t)bh*T + j],
                  colacc[0][j]+colacc[1][j]+colacc[2][j]+colacc[3][j]);
}

// ---- FUSED row+col: eu_i = 1/(T(Σq·ev + tail)); cacc += q^T·eu ---------------
__global__ __launch_bounds__(256) void row_col(const half_t* __restrict__ c_h,
        const float* __restrict__ ev, const float* __restrict__ sev,
        float* __restrict__ eu, float* __restrict__ cacc) {
    int qt = blockIdx.x >> 1, half = blockIdx.x & 1, bh = blockIdx.y;
    int tid = threadIdx.x, lane = tid & 63, w = tid >> 6;
    int span = (qt + 1) * 64, nch = span >> 3;
    __shared__ float colacc[4][2048];
    float evreg[32], acc32[32];
#pragma unroll
    for (int k = 0; k < 32; ++k) acc32[k] = 0.f;
    const float* evb = ev + (size_t)bh * T;
#pragma unroll
    for (int k = 0; k < 4; ++k) {
        int ch = lane + (k << 6);
        if (ch < nch) {
            float4 e0 = *(const float4*)(evb + ch*8);
            float4 e1 = *(const float4*)(evb + ch*8 + 4);
            evreg[k*8+0]=e0.x; evreg[k*8+1]=e0.y; evreg[k*8+2]=e0.z; evreg[k*8+3]=e0.w;
            evreg[k*8+4]=e1.x; evreg[k*8+5]=e1.y; evreg[k*8+6]=e1.z; evreg[k*8+7]=e1.w;
        }
    }
    float tail = sev[bh*33 + qt + 1];
    const half_t* cb = c_h + ((size_t)bh * T + qt * 64 + half * 32) * T;
    for (int rr = 0; rr < 8; ++rr) {
        int i = w * 8 + rr;
        const half_t* crow = cb + (size_t)i * T;
        uint4 raw[4];
        float s = 0.f;
#pragma unroll
        for (int k = 0; k < 4; ++k) {
            int ch = lane + (k << 6);
            if (ch < nch) {
                uint4 rw = *(const uint4*)(crow + ch * 8);
                raw[k] = rw;
                const __half2* h2 = (const __half2*)&rw;
#pragma unroll
                for (int pp = 0; pp < 4; ++pp) {
                    float2 cf = __half22float2(h2[pp]);
                    s = fmaf(cf.x, evreg[k*8+pp*2],   s);
                    s = fmaf(cf.y, evreg[k*8+pp*2+1], s);
                }
            }
        }
        s = wave_allreduce_sum(s);
        float eui = 1.f / (2048.f * (s + tail));
        if (lane == 0) eu[(size_t)bh * T + qt * 64 + half * 32 + i] = eui;
#pragma unroll
        for (int k = 0; k < 4; ++k) {
            int ch = lane + (k << 6);
            if (ch < nch) {
                const __half2* h2 = (const __half2*)&raw[k];
#pragma unroll
                for (int pp = 0; pp < 4; ++pp) {
                    float2 cf = __half22float2(h2[pp]);
                    acc32[k*8+pp*2]   = fmaf(cf.x, eui, acc32[k*8+pp*2]);
                    acc32[k*8+pp*2+1] = fmaf(cf.y, eui, acc32[k*8+pp*2+1]);
                }
            }
        }
    }
#pragma unroll
    for (int k = 0; k < 4; ++k) {
        int ch = lane + (k << 6);
        if (ch < nch)
#pragma unroll
            for (int e = 0; e < 8; ++e)
                colacc[w][ch*8+e] = acc32[k*8+e];
    }
    __syncthreads();
    for (int j = tid; j < span; j += 256)
        atomicAdd(&cacc[(size_t)bh*T + j],
                  colacc[0][j]+colacc[1][j]+colacc[2][j]+colacc[3][j]);
}

// ---- v-finalize (per bh): ev = 1/(T(cacc+prefix(eu))); sev suffix; cacc=0 ----
__global__ __launch_bounds__(256) void v_fin_full(float* __restrict__ cacc,
        const float* __restrict__ eu, float* __restrict__ ev,
        float* __restrict__ sev) {
    int bh = blockIdx.x;
    int tid = threadIdx.x;
    __shared__ float part[256];
    __shared__ float pre[33];
    __shared__ float ts2[32];
    const float* eub = eu + (size_t)bh * T;
    float* caccb = cacc + (size_t)bh * T;
    float* evb = ev + (size_t)bh * T;
    float a = 0.f;
#pragma unroll
    for (int e = 0; e < 8; ++e) a += eub[tid*8 + e];
    part[tid] = a;
    __syncthreads();
    if (tid == 0) {
        float run = 0.f;
        for (int kt = 0; kt < 32; ++kt) {
            pre[kt] = run;
            float t0 = 0.f;
            for (int k = 0; k < 8; ++k) t0 += part[kt*8 + k];
            run += t0;
        }
        pre[32] = run;
    }
    __syncthreads();
    float p = pre[tid >> 3];           // tile of j = tid*8 .. tid*8+7
    float b2 = 0.f;
#pragma unroll
    for (int e = 0; e < 8; ++e) {
        int j = tid*8 + e;
        float vj = 1.f / (2048.f * (caccb[j] + p));
        evb[j] = vj;
        caccb[j] = 0.f;
        b2 += vj;
    }
    part[tid] = b2;
    __syncthreads();
    if (tid < 32) {
        float t0 = 0.f;
#pragma unroll
        for (int k = 0; k < 8; ++k) t0 += part[tid*8 + k];
        ts2[tid] = t0;
    }
    __syncthreads();
    if (tid == 0) {
        float run = 0.f;
        sev[bh*33 + 32] = 0.f;
        for (int kt = 31; kt >= 0; --kt) { run += ts2[kt]; sev[bh*33 + kt] = run; }
    }
}

// ---------------- Wsuf[kt][d] = sum_{tiles jt>=kt} sum_j ev_j V[j][d] ---------
__global__ __launch_bounds__(256) void wv_suffix_kernel(const _Float16* __restrict__ vh,
        const float* __restrict__ ev, float* __restrict__ wsuf) {
    int bh = blockIdx.x;
    int tid = threadIdx.x;
    int d = tid & 63, g = tid >> 6;
    __shared__ float evs[2048];
    __shared__ float W[32][64];
    __shared__ float red[4][64];
    const float* vb = ev + (size_t)bh * T;
#pragma unroll
    for (int k = 0; k < 8; ++k) evs[tid + k*256] = vb[tid + k*256];
    __syncthreads();
    const _Float16* vbase = vh + (size_t)bh * T * 64;
    for (int jt = 0; jt < 32; ++jt) {
        float a = 0.f;
#pragma unroll
        for (int jj = 0; jj < 16; ++jj) {
            int j = jt*64 + g*16 + jj;
            a += evs[j] * (float)vbase[(size_t)j * 64 + d];
        }
        red[g][d] = a;
        __syncthreads();
        if (g == 0) W[jt][d] = red[0][d] + red[1][d] + red[2][d] + red[3][d];
        __syncthreads();
    }
    if (tid < 64) {
        float run = 0.f;
        wsuf[((size_t)bh*33 + 32)*64 + tid] = 0.f;
        for (int kt = 31; kt >= 0; --kt) {
            run += W[kt][tid];
            wsuf[((size_t)bh*33 + kt)*64 + tid] = run;
        }
    }
}

// ---------------- pv split-K: P = q * (eu*T) * ev, MFMA, f32 atomic accum -----
__global__ __launch_bounds__(256) void pv_split(const half_t* __restrict__ c_h,
        const float* __restrict__ eu, const float* __restrict__ ev,
        const _Float16* __restrict__ vh, const float* __restrict__ wsuf,
        float* __restrict__ y32) {
    int qt = blockIdx.x, kc = blockIdx.y, bh = blockIdx.z;
    int j0 = kc * 8;
    if (j0 > qt) return;
    int jend = min(qt + 1, j0 + 8);
    int b = bh / H, h = bh - b * H;
    int tid = threadIdx.x, lane = tid & 63, wave = tid >> 6;
    int wr = wave >> 1, wc = wave & 1;
    int lrow = lane & 15, lseg = lane >> 4;
    int orow = (lane >> 4) * 4, ocol = lane & 15;
    __shared__ __align__(16) _Float16 Ps[64][72];
    __shared__ __align__(16) _Float16 Vt[64][72];
    __shared__ float facs[64], vs[64], wsf[64];
    if (tid < 64) {
        facs[tid] = eu[(size_t)bh*T + qt*64 + tid] * 2048.f;
        if (kc == 0) wsf[tid] = wsuf[((size_t)bh*33 + qt + 1)*64 + tid];
    }
    f32x4 acc[2][2] = {};
    const half_t* cb0 = c_h + ((size_t)bh*T + qt*64)*T;
    for (int jt = j0; jt < jend; ++jt) {
        __syncthreads();
        if (tid < 64) vs[tid] = ev[(size_t)bh*T + jt*64 + tid];
        __syncthreads();
        // stage P = q * fac_r * ev_j, f16
#pragma unroll
        for (int k = 0; k < 2; ++k) {
            int cc = k*256 + tid;
            int r = cc >> 3, sg = cc & 7;
            uint4 rw = *(const uint4*)&cb0[(size_t)r*T + jt*64 + sg*8];
            const __half2* h2 = (const __half2*)&rw;
            float fr = facs[r];
            f16x8 p8;
#pragma unroll
            for (int pp = 0; pp < 4; ++pp) {
                float2 cf = __half22float2(h2[pp]);
                p8[pp*2]   = (_Float16)(cf.x * fr * vs[sg*8 + pp*2]);
                p8[pp*2+1] = (_Float16)(cf.y * fr * vs[sg*8 + pp*2 + 1]);
            }
            *(f16x8*)&Ps[r][sg*8] = p8;
        }
        // stage V^T: conflict-free b16 writes
        {
            const _Float16* vb = vh + ((size_t)bh*T + jt*64)*64;
#pragma unroll
            for (int k = 0; k < 2; ++k) {
                int d8 = (wave*2 + k) * 8;
                f16x8 v8 = *(const f16x8*)&vb[(size_t)lane*64 + d8];
#pragma unroll
                for (int e = 0; e < 8; ++e) Vt[d8 + e][lane] = v8[e];
            }
        }
        __syncthreads();
        f16x8 af[2], bf[2];
#pragma unroll
        for (int i = 0; i < 2; ++i) af[i] = *(const f16x8*)&Ps[wr*32+i*16+lrow][lseg*8];
#pragma unroll
        for (int j = 0; j < 2; ++j) bf[j] = *(const f16x8*)&Vt[wc*32+j*16+lrow][lseg*8];
#pragma unroll
        for (int i = 0; i < 2; ++i)
#pragma unroll
            for (int j = 0; j < 2; ++j)
                acc[i][j] = __builtin_amdgcn_mfma_f32_16x16x32_f16(af[i], bf[j], acc[i][j], 0,0,0);
#pragma unroll
        for (int i = 0; i < 2; ++i) af[i] = *(const f16x8*)&Ps[wr*32+i*16+lrow][32+lseg*8];
#pragma unroll
        for (int j = 0; j < 2; ++j) bf[j] = *(const f16x8*)&Vt[wc*32+j*16+lrow][32+lseg*8];
#pragma unroll
        for (int i = 0; i < 2; ++i)
#pragma unroll
            for (int j = 0; j < 2; ++j)
                acc[i][j] = __builtin_amdgcn_mfma_f32_16x16x32_f16(af[i], bf[j], acc[i][j], 0,0,0);
    }
#pragma unroll
    for (int i = 0; i < 2; ++i)
#pragma unroll
        for (int j = 0; j < 2; ++j)
#pragma unroll
            for (int r = 0; r < 4; ++r) {
                int rl = wr*32 + i*16 + orow + r;
                int cl = wc*32 + j*16 + ocol;
                float val = acc[i][j][r];
                if (kc == 0) val += facs[rl] * wsf[cl];
                atomicAdd(&y32[((size_t)b*T + qt*64 + rl)*C + h*HD + cl], val);
            }
}

// -----------------------------------------------------------------------------
extern "C" void kernel_launch(void* const* d_in, const int* in_sizes, int n_in,
                              void* d_out, int out_size, void* d_ws, size_t ws_size,
                              hipStream_t stream) {
    (void)in_sizes; (void)n_in; (void)out_size;
    const float* x      = (const float*)d_in[0];
    const float* t      = (const float*)d_in[1];
    const float* ln1_w  = (const float*)d_in[2];
    const float* ln1_b  = (const float*)d_in[3];
    const float* attn_w = (const float*)d_in[4];
    const float* attn_b = (const float*)d_in[5];
    const float* proj_w = (const float*)d_in[6];
    const float* proj_b = (const float*)d_in[7];
    const float* ln2_w  = (const float*)d_in[8];
    const float* ln2_b  = (const float*)d_in[9];
    const float* fc_w   = (const float*)d_in[10];
    const float* fc_b   = (const float*)d_in[11];
    const float* fc2_w  = (const float*)d_in[12];
    const float* fc2_b  = (const float*)d_in[13];
    float* out = (float*)d_out;

    // ---- workspace layout (121,482,240 bytes) ----
    if (ws_size < 121482240ull) return;
    char* wsb = (char*)d_ws;
    half_t*    c_h  = (half_t*)wsb;                          // 100,663,296
    _Float16*  qkvh = (_Float16*)(wsb + 100663296ull);       // 9,437,184: q|k|v head-major
    float*     y32  = (float*)(wsb + 110100480ull);          // 6,291,456
    _Float16*  xh   = (_Float16*)(wsb + 116391936ull);       // 3,407,872
    _Float16*  wbuf = (_Float16*)(wsb + 119799808ull);       // 1,277,952
    float*     eu   = (float*)(wsb + 121077760ull);          // BHT
    float*     ev   = eu   + BHT;
    float*     cacc = ev   + BHT;
    float*     sev  = cacc + BHT;                            // 12*33 (+pad)
    float*     wsuf = sev  + 1024;                           // 12*33*64
    // aliases:
    const _Float16* qh = qkvh;
    const _Float16* kh = qkvh + (size_t)(B*H) * T * 64;
    const _Float16* vh = qkvh + (size_t)2 * (B*H) * T * 64;
    _Float16* xn_h = xh;               // ln1 out -> qkv gemm in
    _Float16* hn_h = xh;               // ln2 out -> fc in (xh dead)
    float*    hb   = (float*)qkvh;     // proj out (qkvh dead after pv)
    _Float16* mb_h = (_Float16*)wsb;   // fc out (c dead after pv)

    const int M = B * T;   // 4096
    const int KP1 = 416;   // (C+1) padded to 32

    // ---- attention sub-block ----
    addtime_ln_f16<<<M, 256, 0, stream>>>(x, t, ln1_w, ln1_b, xn_h, KP1);
    convtrans_kernel<<<dim3(KP1/32, (3*C)/32), 256, 0, stream>>>(attn_w, wbuf, C+1, 3*C, KP1);
    mfma_gemm<0, 1, _Float16, _Float16><<<dim3(3*C/64, M/64), 256, 0, stream>>>(
        xn_h, wbuf, attn_b, qkvh, M, 3*C, KP1);
    qk_tileA<<<dim3(528, B*H), 256, 0, stream>>>(qh, kh, c_h);

    // ---- multiplicative sinkhorn, fused passes ----
    zerof_kernel<<<BHT/256, 256, 0, stream>>>(cacc);
    norm_q_col<<<dim3(64, B*H), 256, 0, stream>>>(c_h, eu, cacc);      // q, eu0, colacc
    v_fin_full<<<B*H, 256, 0, stream>>>(cacc, eu, ev, sev);            // ev1 (+sev, cacc=0)
    row_col<<<dim3(64, B*H), 256, 0, stream>>>(c_h, ev, sev, eu, cacc);// eu2, colacc
    v_fin_full<<<B*H, 256, 0, stream>>>(cacc, eu, ev, sev);            // ev3
    row_col<<<dim3(64, B*H), 256, 0, stream>>>(c_h, ev, sev, eu, cacc);// eu4, colacc
    v_fin_full<<<B*H, 256, 0, stream>>>(cacc, eu, ev, sev);            // ev5

    wv_suffix_kernel<<<B*H, 256, 0, stream>>>(vh, ev, wsuf);
    zerof_kernel<<<(M*C)/256, 256, 0, stream>>>(y32);
    pv_split<<<dim3(T/64, 4, B*H), 256, 0, stream>>>(c_h, eu, ev, vh, wsuf, y32);

    convtrans_kernel<<<dim3(C/32, C/32), 256, 0, stream>>>(proj_w, wbuf, C, C, C);
    mfma_gemm<0, 0, float, float><<<dim3(C/64, M/64), 256, 0, stream>>>(
        y32, wbuf, proj_b, hb, M, C, C);

    // ---- MLP sub-block ----
    addtime_ln_f16<<<M, 256, 0, stream>>>(hb, t, ln2_w, ln2_b, hn_h, KP1);
    convtrans_kernel<<<dim3(KP1/32, (4*C)/32), 256, 0, stream>>>(fc_w, wbuf, C+1, 4*C, KP1);
    mfma_gemm<1, 0, _Float16, _Float16><<<dim3(4*C/64, M/64), 256, 0, stream>>>(
        hn_h, wbuf, fc_b, mb_h, M, 4*C, KP1);
    convtrans_kernel<<<dim3((4*C)/32, C/32), 256, 0, stream>>>(fc2_w, wbuf, 4*C, C, 4*C);
    mfma_gemm<0, 0, _Float16, float><<<dim3(C/64, M/64), 256, 0, stream>>>(
        mb_h, wbuf, fc2_b, out, M, C, 4*C);
}